// Round 5
// baseline (339.017 us; speedup 1.0000x reference)
//
#include <hip/hip_runtime.h>
#include <math.h>

#define N_NODES 50000
#define N_EDGES 800000
#define HD 128
#define BN_EPS 1e-5f

#define SCAN_CHUNK 1024                       // elements per scan block
#define SCAN_NB ((N_NODES + SCAN_CHUNK - 1) / SCAN_CHUNK)  // 49
#define TILE_R 32                             // gemm rows per block

// K1: dst-degree histogram.  4 edges/thread via int4.
__global__ __launch_bounds__(256) void hist(const int* __restrict__ dst,
                                            int* __restrict__ counts) {
  int i = blockIdx.x * 256 + threadIdx.x;
  if (i >= N_EDGES / 4) return;
  int4 d = ((const int4*)dst)[i];
  atomicAdd(counts + d.x, 1);
  atomicAdd(counts + d.y, 1);
  atomicAdd(counts + d.z, 1);
  atomicAdd(counts + d.w, 1);
}

// K2a: per-block partial sums of counts (1024 elements / block).
__global__ __launch_bounds__(256) void scan_blocks(
    const int* __restrict__ counts, int* __restrict__ bsum) {
  int t = threadIdx.x;
  int idx = blockIdx.x * SCAN_CHUNK + t * 4;
  int s = 0;
  if (idx + 3 < N_NODES) {
    int4 v = *(const int4*)(counts + idx);
    s = v.x + v.y + v.z + v.w;
  } else {
#pragma unroll
    for (int j = 0; j < 4; ++j)
      if (idx + j < N_NODES) s += counts[idx + j];
  }
  __shared__ int ls[256];
  ls[t] = s;
  __syncthreads();
  for (int off = 128; off > 0; off >>= 1) {
    if (t < off) ls[t] += ls[t + off];
    __syncthreads();
  }
  if (t == 0) bsum[blockIdx.x] = ls[0];
}

// K2b: one wave scans the SCAN_NB partials -> exclusive bases + grand total.
__global__ __launch_bounds__(64) void scan_top(const int* __restrict__ bsum,
                                               int* __restrict__ bbase,
                                               int* __restrict__ offsets) {
  int t = threadIdx.x;
  int v = (t < SCAN_NB) ? bsum[t] : 0;
  int incl = v;
#pragma unroll
  for (int off = 1; off < 64; off <<= 1) {
    int u = __shfl_up(incl, off, 64);
    if (t >= off) incl += u;
  }
  if (t < SCAN_NB) bbase[t] = incl - v;
  if (t == 63) offsets[N_NODES] = incl;  // grand total
}

// K2c: per-block exclusive scan + base -> offsets.
__global__ __launch_bounds__(256) void scan_write(
    const int* __restrict__ counts, const int* __restrict__ bbase,
    int* __restrict__ offsets) {
  int t = threadIdx.x;
  int idx = blockIdx.x * SCAN_CHUNK + t * 4;
  int c[4] = {0, 0, 0, 0};
  if (idx + 3 < N_NODES) {
    int4 v = *(const int4*)(counts + idx);
    c[0] = v.x; c[1] = v.y; c[2] = v.z; c[3] = v.w;
  } else {
#pragma unroll
    for (int j = 0; j < 4; ++j)
      if (idx + j < N_NODES) c[j] = counts[idx + j];
  }
  int s = c[0] + c[1] + c[2] + c[3];
  __shared__ int ls[256];
  ls[t] = s;
  __syncthreads();
  for (int off = 1; off < 256; off <<= 1) {
    int u = (t >= off) ? ls[t - off] : 0;
    __syncthreads();
    ls[t] += u;
    __syncthreads();
  }
  int run = bbase[blockIdx.x] + ls[t] - s;
#pragma unroll
  for (int j = 0; j < 4; ++j) {
    if (idx + j < N_NODES) {
      offsets[idx + j] = run;
      run += c[j];
    }
  }
}

// K3: bucket edges by dst, packing {src, rid} into 8B records.
__global__ __launch_bounds__(256) void fill_buckets(
    const int* __restrict__ src, const int* __restrict__ dst,
    const int* __restrict__ rid, const int* __restrict__ offsets,
    int* __restrict__ cursor, int2* __restrict__ einfo) {
  int i = blockIdx.x * 256 + threadIdx.x;
  if (i >= N_EDGES / 4) return;
  int4 s4 = ((const int4*)src)[i];
  int4 d4 = ((const int4*)dst)[i];
  int4 r4 = ((const int4*)rid)[i];
#pragma unroll
  for (int q = 0; q < 4; ++q) {
    int s = (q == 0) ? s4.x : (q == 1) ? s4.y : (q == 2) ? s4.z : s4.w;
    int d = (q == 0) ? d4.x : (q == 1) ? d4.y : (q == 2) ? d4.z : d4.w;
    int r = (q == 0) ? r4.x : (q == 1) ? r4.y : (q == 2) ? r4.z : r4.w;
    int pos = atomicAdd(cursor + d, 1);
    einfo[offsets[d] + pos] = make_int2(s, r);
  }
}

// K4: fused score + online-softmax + aggregation.  One wave per dst node,
// edge loop unrolled x4.
__global__ __launch_bounds__(256) void gather_fused(
    const float* __restrict__ ent, const float* __restrict__ rel,
    const int* __restrict__ offsets, const int2* __restrict__ einfo,
    float* __restrict__ scaled) {
  int n = blockIdx.x * 4 + (threadIdx.x >> 6);
  if (n >= N_NODES) return;
  int lane = threadIdx.x & 63;
  int s0 = __builtin_amdgcn_readfirstlane(offsets[n]);
  int s1 = __builtin_amdgcn_readfirstlane(offsets[n + 1]);
  float2 b = ((const float2*)(ent + (long)n * HD))[lane];
  float m = -INFINITY, den = 0.f, ax = 0.f, ay = 0.f;
  int s = s0;
  for (; s + 4 <= s1; s += 4) {
    int2 v0 = einfo[s + 0];
    int2 v1 = einfo[s + 1];
    int2 v2 = einfo[s + 2];
    int2 v3 = einfo[s + 3];
    float2 a0 = ((const float2*)(ent + (long)v0.x * HD))[lane];
    float2 c0 = ((const float2*)(rel + (long)v0.y * HD))[lane];
    float2 a1 = ((const float2*)(ent + (long)v1.x * HD))[lane];
    float2 c1 = ((const float2*)(rel + (long)v1.y * HD))[lane];
    float2 a2 = ((const float2*)(ent + (long)v2.x * HD))[lane];
    float2 c2 = ((const float2*)(rel + (long)v2.y * HD))[lane];
    float2 a3 = ((const float2*)(ent + (long)v3.x * HD))[lane];
    float2 c3 = ((const float2*)(rel + (long)v3.y * HD))[lane];
    float cx0 = a0.x * c0.x, cy0 = a0.y * c0.y;
    float cx1 = a1.x * c1.x, cy1 = a1.y * c1.y;
    float cx2 = a2.x * c2.x, cy2 = a2.y * c2.y;
    float cx3 = a3.x * c3.x, cy3 = a3.y * c3.y;
    float p0 = cx0 * b.x + cy0 * b.y;
    float p1 = cx1 * b.x + cy1 * b.y;
    float p2 = cx2 * b.x + cy2 * b.y;
    float p3 = cx3 * b.x + cy3 * b.y;
#pragma unroll
    for (int off = 32; off > 0; off >>= 1) {
      p0 += __shfl_xor(p0, off, 64);
      p1 += __shfl_xor(p1, off, 64);
      p2 += __shfl_xor(p2, off, 64);
      p3 += __shfl_xor(p3, off, 64);
    }
    float pm = fmaxf(fmaxf(fmaxf(p0, p1), fmaxf(p2, p3)), m);
    float f = __expf(m - pm);
    float e0 = __expf(p0 - pm);
    float e1 = __expf(p1 - pm);
    float e2 = __expf(p2 - pm);
    float e3 = __expf(p3 - pm);
    den = den * f + ((e0 + e1) + (e2 + e3));
    ax = ax * f + cx0 * e0 + cx1 * e1 + cx2 * e2 + cx3 * e3;
    ay = ay * f + cy0 * e0 + cy1 * e1 + cy2 * e2 + cy3 * e3;
    m = pm;
  }
  for (; s < s1; ++s) {
    int2 v = einfo[s];
    float2 a = ((const float2*)(ent + (long)v.x * HD))[lane];
    float2 c = ((const float2*)(rel + (long)v.y * HD))[lane];
    float cx = a.x * c.x, cy = a.y * c.y;
    float p = cx * b.x + cy * b.y;
#pragma unroll
    for (int off = 32; off > 0; off >>= 1) p += __shfl_xor(p, off, 64);
    float mn = fmaxf(m, p);
    float f = __expf(m - mn);
    float e = __expf(p - mn);
    den = den * f + e;
    ax = ax * f + cx * e;
    ay = ay * f + cy * e;
    m = mn;
  }
  float inv = den > 0.f ? 1.f / den : 0.f;
  ((float2*)(scaled + (long)n * HD))[lane] = make_float2(ax * inv, ay * inv);
}

__device__ __forceinline__ float f4_get(const float4& v, int k) {
  return k == 0 ? v.x : k == 1 ? v.y : k == 2 ? v.z : v.w;
}

// K5: h = scaled @ W with fused column sum/sumsq.
// Conflict-free layout: cols c = lane&31 (stride-1 float4 over W row);
// scaled tile stored rotated sN4[r][(k4+r)&31]; row-groups at stride 8 so
// the 8 broadcast a-reads per instruction hit 8 distinct bank groups.
__global__ __launch_bounds__(256) void gemm_stats(
    const float* __restrict__ scaled, const float* __restrict__ W,
    float* __restrict__ h, float* __restrict__ colsum,
    float* __restrict__ colsumsq) {
  __shared__ float4 sW4[HD * 32];      // 64 KB: sW4[k*32+c] = W[k][4c..4c+3]
  __shared__ float4 sN4[TILE_R * 32];  // 16 KB, rotated
  int tid = threadIdx.x;
  int row0 = blockIdx.x * TILE_R;
  for (int i = tid; i < TILE_R * 32; i += 256) {
    int r = i >> 5, k4 = i & 31;
    int gr = row0 + r;
    float4 v = make_float4(0.f, 0.f, 0.f, 0.f);
    if (gr < N_NODES) v = ((const float4*)scaled)[(long)gr * 32 + k4];
    sN4[r * 32 + ((k4 + r) & 31)] = v;
  }
  for (int i = tid; i < HD * 32; i += 256) sW4[i] = ((const float4*)W)[i];
  __syncthreads();

  int lane = tid & 63;
  int c = lane & 31;                         // col group: cols 4c..4c+3
  int g = ((tid >> 6) << 1) | (lane >> 5);   // row group 0..7
  float4 acc[4];
#pragma unroll
  for (int rr = 0; rr < 4; ++rr) acc[rr] = make_float4(0.f, 0.f, 0.f, 0.f);

  for (int k4 = 0; k4 < 32; ++k4) {
    float4 a[4];
#pragma unroll
    for (int rr = 0; rr < 4; ++rr) {
      int r = g + 8 * rr;
      a[rr] = sN4[r * 32 + ((k4 + r) & 31)];
    }
#pragma unroll
    for (int kk = 0; kk < 4; ++kk) {
      float4 w4 = sW4[(k4 * 4 + kk) * 32 + c];
#pragma unroll
      for (int rr = 0; rr < 4; ++rr) {
        float av = f4_get(a[rr], kk);
        acc[rr].x = fmaf(av, w4.x, acc[rr].x);
        acc[rr].y = fmaf(av, w4.y, acc[rr].y);
        acc[rr].z = fmaf(av, w4.z, acc[rr].z);
        acc[rr].w = fmaf(av, w4.w, acc[rr].w);
      }
    }
  }

  // store h + per-thread partial stats
  float4 s = make_float4(0.f, 0.f, 0.f, 0.f);
  float4 q = make_float4(0.f, 0.f, 0.f, 0.f);
#pragma unroll
  for (int rr = 0; rr < 4; ++rr) {
    int gr = row0 + g + 8 * rr;
    if (gr < N_NODES) {
      ((float4*)h)[(long)gr * 32 + c] = acc[rr];
      s.x += acc[rr].x; s.y += acc[rr].y; s.z += acc[rr].z; s.w += acc[rr].w;
      q.x += acc[rr].x * acc[rr].x; q.y += acc[rr].y * acc[rr].y;
      q.z += acc[rr].z * acc[rr].z; q.w += acc[rr].w * acc[rr].w;
    }
  }
  __syncthreads();  // sN4 dead; reuse as stats buffer (8 KB of 16 KB)
  float4* sSum = (float4*)sN4;        // [8][32]
  float4* sSq  = ((float4*)sN4) + 256;
  sSum[g * 32 + c] = s;
  sSq[g * 32 + c] = q;
  __syncthreads();
  if (tid < 32) {
    float4 S = make_float4(0.f, 0.f, 0.f, 0.f);
    float4 Q = make_float4(0.f, 0.f, 0.f, 0.f);
#pragma unroll
    for (int gg = 0; gg < 8; ++gg) {
      float4 u = sSum[gg * 32 + tid];
      float4 v = sSq[gg * 32 + tid];
      S.x += u.x; S.y += u.y; S.z += u.z; S.w += u.w;
      Q.x += v.x; Q.y += v.y; Q.z += v.z; Q.w += v.w;
    }
    unsafeAtomicAdd(colsum + tid * 4 + 0, S.x);
    unsafeAtomicAdd(colsum + tid * 4 + 1, S.y);
    unsafeAtomicAdd(colsum + tid * 4 + 2, S.z);
    unsafeAtomicAdd(colsum + tid * 4 + 3, S.w);
    unsafeAtomicAdd(colsumsq + tid * 4 + 0, Q.x);
    unsafeAtomicAdd(colsumsq + tid * 4 + 1, Q.y);
    unsafeAtomicAdd(colsumsq + tid * 4 + 2, Q.z);
    unsafeAtomicAdd(colsumsq + tid * 4 + 3, Q.w);
  }
}

// K6: BN (batch stats) + tanh, h (ws) -> out.
__global__ __launch_bounds__(256) void bn_tanh(
    const float* __restrict__ h, const float* __restrict__ colsum,
    const float* __restrict__ colsumsq, const float* __restrict__ gamma,
    const float* __restrict__ beta, float* __restrict__ out) {
  const float invN = 1.f / (float)N_NODES;
  long total = (long)N_NODES * HD;
  for (long i = (long)blockIdx.x * blockDim.x + threadIdx.x; i < total;
       i += (long)gridDim.x * blockDim.x) {
    int c = (int)(i & 127);
    float mu = colsum[c] * invN;
    float var = colsumsq[c] * invN - mu * mu;
    float v = (h[i] - mu) * rsqrtf(var + BN_EPS) * gamma[c] + beta[c];
    out[i] = tanhf(v);
  }
}

extern "C" void kernel_launch(void* const* d_in, const int* in_sizes, int n_in,
                              void* d_out, int out_size, void* d_ws, size_t ws_size,
                              hipStream_t stream) {
  const float* ent   = (const float*)d_in[0];
  const float* rel   = (const float*)d_in[1];
  const float* W     = (const float*)d_in[2];
  const float* gamma = (const float*)d_in[3];
  const float* beta  = (const float*)d_in[4];
  const int*   src   = (const int*)d_in[5];
  const int*   dst   = (const int*)d_in[6];
  const int*   rid   = (const int*)d_in[7];
  float* out = (float*)d_out;

  char* ws = (char*)d_ws;
  int* counts      = (int*)(ws + 0);           // 200,000 B
  int* cursor      = (int*)(ws + 200000);      // 200,000 B
  float* colsum    = (float*)(ws + 400000);    // 512 B
  float* colsumsq  = (float*)(ws + 400512);    // 512 B   (zeroed region ends 401,024)
  int* bsum        = (int*)(ws + 401024);      // 1,024 B
  int* bbase       = (int*)(ws + 402048);      // 1,024 B
  int* offsets     = (int*)(ws + 403072);      // 200,004 B -> 603,076
  // einfo (6.4 MB) and h (25.6 MB) share a region: einfo is dead before
  // gemm_stats writes h (strict stream ordering).
  int2* einfo      = (int2*)(ws + 603136);     // 6,400,000 B
  float* h         = (float*)(ws + 603136);    // 25,600,000 B -> 26,203,136 total
  float* scaled    = out;                      // gather result lives in d_out

  // zero: counts, cursor, colsum, colsumsq
  hipMemsetAsync(d_ws, 0, 401024, stream);

  hist<<<(N_EDGES / 4 + 255) / 256, 256, 0, stream>>>(dst, counts);
  scan_blocks<<<SCAN_NB, 256, 0, stream>>>(counts, bsum);
  scan_top<<<1, 64, 0, stream>>>(bsum, bbase, offsets);
  scan_write<<<SCAN_NB, 256, 0, stream>>>(counts, bbase, offsets);
  fill_buckets<<<(N_EDGES / 4 + 255) / 256, 256, 0, stream>>>(src, dst, rid,
                                                              offsets, cursor, einfo);
  gather_fused<<<(N_NODES + 3) / 4, 256, 0, stream>>>(ent, rel, offsets, einfo,
                                                      scaled);
  gemm_stats<<<(N_NODES + TILE_R - 1) / TILE_R, 256, 0, stream>>>(
      scaled, W, h, colsum, colsumsq);
  bn_tanh<<<2048, 256, 0, stream>>>(h, colsum, colsumsq, gamma, beta, out);
}

// Round 6
// 263.461 us; speedup vs baseline: 1.2868x; 1.2868x over previous
//
#include <hip/hip_runtime.h>
#include <math.h>

#define N_NODES 50000
#define N_EDGES 800000
#define HD 128
#define BN_EPS 1e-5f

#define SCAN_CHUNK 1024                       // elements per scan block
#define SCAN_NB ((N_NODES + SCAN_CHUNK - 1) / SCAN_CHUNK)  // 49

#define GR 64        // gemm rows per block
#define GC 64        // gemm cols per block
#define SN_STRIDE 68 // k-major row stride (floats): 64 rows + 4 pad, 16B-aligned, conflict-free

// K1: dst-degree histogram.  4 edges/thread via int4.
__global__ __launch_bounds__(256) void hist(const int* __restrict__ dst,
                                            int* __restrict__ counts) {
  int i = blockIdx.x * 256 + threadIdx.x;
  if (i >= N_EDGES / 4) return;
  int4 d = ((const int4*)dst)[i];
  atomicAdd(counts + d.x, 1);
  atomicAdd(counts + d.y, 1);
  atomicAdd(counts + d.z, 1);
  atomicAdd(counts + d.w, 1);
}

// K2a: per-block partial sums of counts (1024 elements / block).
__global__ __launch_bounds__(256) void scan_blocks(
    const int* __restrict__ counts, int* __restrict__ bsum) {
  int t = threadIdx.x;
  int idx = blockIdx.x * SCAN_CHUNK + t * 4;
  int s = 0;
  if (idx + 3 < N_NODES) {
    int4 v = *(const int4*)(counts + idx);
    s = v.x + v.y + v.z + v.w;
  } else {
#pragma unroll
    for (int j = 0; j < 4; ++j)
      if (idx + j < N_NODES) s += counts[idx + j];
  }
  __shared__ int ls[256];
  ls[t] = s;
  __syncthreads();
  for (int off = 128; off > 0; off >>= 1) {
    if (t < off) ls[t] += ls[t + off];
    __syncthreads();
  }
  if (t == 0) bsum[blockIdx.x] = ls[0];
}

// K2b: one wave scans the SCAN_NB partials -> exclusive bases + grand total.
__global__ __launch_bounds__(64) void scan_top(const int* __restrict__ bsum,
                                               int* __restrict__ bbase,
                                               int* __restrict__ offsets) {
  int t = threadIdx.x;
  int v = (t < SCAN_NB) ? bsum[t] : 0;
  int incl = v;
#pragma unroll
  for (int off = 1; off < 64; off <<= 1) {
    int u = __shfl_up(incl, off, 64);
    if (t >= off) incl += u;
  }
  if (t < SCAN_NB) bbase[t] = incl - v;
  if (t == 63) offsets[N_NODES] = incl;  // grand total
}

// K2c: per-block exclusive scan + base -> offsets.
__global__ __launch_bounds__(256) void scan_write(
    const int* __restrict__ counts, const int* __restrict__ bbase,
    int* __restrict__ offsets) {
  int t = threadIdx.x;
  int idx = blockIdx.x * SCAN_CHUNK + t * 4;
  int c[4] = {0, 0, 0, 0};
  if (idx + 3 < N_NODES) {
    int4 v = *(const int4*)(counts + idx);
    c[0] = v.x; c[1] = v.y; c[2] = v.z; c[3] = v.w;
  } else {
#pragma unroll
    for (int j = 0; j < 4; ++j)
      if (idx + j < N_NODES) c[j] = counts[idx + j];
  }
  int s = c[0] + c[1] + c[2] + c[3];
  __shared__ int ls[256];
  ls[t] = s;
  __syncthreads();
  for (int off = 1; off < 256; off <<= 1) {
    int u = (t >= off) ? ls[t - off] : 0;
    __syncthreads();
    ls[t] += u;
    __syncthreads();
  }
  int run = bbase[blockIdx.x] + ls[t] - s;
#pragma unroll
  for (int j = 0; j < 4; ++j) {
    if (idx + j < N_NODES) {
      offsets[idx + j] = run;
      run += c[j];
    }
  }
}

// K3: bucket edges by dst, packing {src, rid} into 8B records.
__global__ __launch_bounds__(256) void fill_buckets(
    const int* __restrict__ src, const int* __restrict__ dst,
    const int* __restrict__ rid, const int* __restrict__ offsets,
    int* __restrict__ cursor, int2* __restrict__ einfo) {
  int i = blockIdx.x * 256 + threadIdx.x;
  if (i >= N_EDGES / 4) return;
  int4 s4 = ((const int4*)src)[i];
  int4 d4 = ((const int4*)dst)[i];
  int4 r4 = ((const int4*)rid)[i];
#pragma unroll
  for (int q = 0; q < 4; ++q) {
    int s = (q == 0) ? s4.x : (q == 1) ? s4.y : (q == 2) ? s4.z : s4.w;
    int d = (q == 0) ? d4.x : (q == 1) ? d4.y : (q == 2) ? d4.z : d4.w;
    int r = (q == 0) ? r4.x : (q == 1) ? r4.y : (q == 2) ? r4.z : r4.w;
    int pos = atomicAdd(cursor + d, 1);
    einfo[offsets[d] + pos] = make_int2(s, r);
  }
}

// K4: fused score + online-softmax + aggregation.  One wave per dst node,
// edge loop unrolled x4.
__global__ __launch_bounds__(256) void gather_fused(
    const float* __restrict__ ent, const float* __restrict__ rel,
    const int* __restrict__ offsets, const int2* __restrict__ einfo,
    float* __restrict__ scaled) {
  int n = blockIdx.x * 4 + (threadIdx.x >> 6);
  if (n >= N_NODES) return;
  int lane = threadIdx.x & 63;
  int s0 = __builtin_amdgcn_readfirstlane(offsets[n]);
  int s1 = __builtin_amdgcn_readfirstlane(offsets[n + 1]);
  float2 b = ((const float2*)(ent + (long)n * HD))[lane];
  float m = -INFINITY, den = 0.f, ax = 0.f, ay = 0.f;
  int s = s0;
  for (; s + 4 <= s1; s += 4) {
    int2 v0 = einfo[s + 0];
    int2 v1 = einfo[s + 1];
    int2 v2 = einfo[s + 2];
    int2 v3 = einfo[s + 3];
    float2 a0 = ((const float2*)(ent + (long)v0.x * HD))[lane];
    float2 c0 = ((const float2*)(rel + (long)v0.y * HD))[lane];
    float2 a1 = ((const float2*)(ent + (long)v1.x * HD))[lane];
    float2 c1 = ((const float2*)(rel + (long)v1.y * HD))[lane];
    float2 a2 = ((const float2*)(ent + (long)v2.x * HD))[lane];
    float2 c2 = ((const float2*)(rel + (long)v2.y * HD))[lane];
    float2 a3 = ((const float2*)(ent + (long)v3.x * HD))[lane];
    float2 c3 = ((const float2*)(rel + (long)v3.y * HD))[lane];
    float cx0 = a0.x * c0.x, cy0 = a0.y * c0.y;
    float cx1 = a1.x * c1.x, cy1 = a1.y * c1.y;
    float cx2 = a2.x * c2.x, cy2 = a2.y * c2.y;
    float cx3 = a3.x * c3.x, cy3 = a3.y * c3.y;
    float p0 = cx0 * b.x + cy0 * b.y;
    float p1 = cx1 * b.x + cy1 * b.y;
    float p2 = cx2 * b.x + cy2 * b.y;
    float p3 = cx3 * b.x + cy3 * b.y;
#pragma unroll
    for (int off = 32; off > 0; off >>= 1) {
      p0 += __shfl_xor(p0, off, 64);
      p1 += __shfl_xor(p1, off, 64);
      p2 += __shfl_xor(p2, off, 64);
      p3 += __shfl_xor(p3, off, 64);
    }
    float pm = fmaxf(fmaxf(fmaxf(p0, p1), fmaxf(p2, p3)), m);
    float f = __expf(m - pm);
    float e0 = __expf(p0 - pm);
    float e1 = __expf(p1 - pm);
    float e2 = __expf(p2 - pm);
    float e3 = __expf(p3 - pm);
    den = den * f + ((e0 + e1) + (e2 + e3));
    ax = ax * f + cx0 * e0 + cx1 * e1 + cx2 * e2 + cx3 * e3;
    ay = ay * f + cy0 * e0 + cy1 * e1 + cy2 * e2 + cy3 * e3;
    m = pm;
  }
  for (; s < s1; ++s) {
    int2 v = einfo[s];
    float2 a = ((const float2*)(ent + (long)v.x * HD))[lane];
    float2 c = ((const float2*)(rel + (long)v.y * HD))[lane];
    float cx = a.x * c.x, cy = a.y * c.y;
    float p = cx * b.x + cy * b.y;
#pragma unroll
    for (int off = 32; off > 0; off >>= 1) p += __shfl_xor(p, off, 64);
    float mn = fmaxf(m, p);
    float f = __expf(m - mn);
    float e = __expf(p - mn);
    den = den * f + e;
    ax = ax * f + cx * e;
    ay = ay * f + cy * e;
    m = mn;
  }
  float inv = den > 0.f ? 1.f / den : 0.f;
  ((float2*)(scaled + (long)n * HD))[lane] = make_float2(ax * inv, ay * inv);
}

// K5: h = scaled @ W with fused column sum/sumsq.
// Tile 64 rows x 64 cols, full K=128.  Per thread: 4x4 outer product.
// sN k-major (stride 68) -> a-read = one float4 of 4 consecutive rows
// (4 distinct addrs/wave = broadcast-cheap); sW4 natural -> w-read =
// 16 consecutive float4 (2x alias = free).  ~2 B LDS per FMA -> VALU-bound.
// LDS = 34 KB + 32 KB = 66 KB -> 2 blocks/CU.
__global__ __launch_bounds__(256) void gemm_stats(
    const float* __restrict__ scaled, const float* __restrict__ W,
    float* __restrict__ h, float* __restrict__ colsum,
    float* __restrict__ colsumsq) {
  __shared__ float4 sNbuf[(128 * SN_STRIDE) / 4];  // 34,816 B
  __shared__ float4 sW4[128 * (GC / 4)];           // 32,768 B
  float* sN = (float*)sNbuf;
  int tid = threadIdx.x;
  int rowblk = blockIdx.x >> 1;
  int colblk = blockIdx.x & 1;
  int row0 = rowblk * GR;
  int col0 = colblk * GC;

  // stage W half-columns: sW4[k*16+cg] = W[k][col0+4cg .. +3]
  for (int i = tid; i < 128 * 16; i += 256) {
    int k = i >> 4, cg = i & 15;
    sW4[i] = ((const float4*)W)[k * 32 + (col0 >> 2) + cg];
  }
  // stage scaled rows, transposed to k-major: sN[k*68 + r]
  {
    int r = tid >> 2;   // 0..63
    int kq = tid & 3;
    int gr = row0 + r;
#pragma unroll
    for (int it = 0; it < 8; ++it) {
      int k4 = kq + it * 4;  // 0..31
      float4 v = make_float4(0.f, 0.f, 0.f, 0.f);
      if (gr < N_NODES) v = ((const float4*)scaled)[(long)gr * 32 + k4];
      sN[(k4 * 4 + 0) * SN_STRIDE + r] = v.x;
      sN[(k4 * 4 + 1) * SN_STRIDE + r] = v.y;
      sN[(k4 * 4 + 2) * SN_STRIDE + r] = v.z;
      sN[(k4 * 4 + 3) * SN_STRIDE + r] = v.w;
    }
  }
  __syncthreads();

  int cg = tid & 15;   // cols col0 + 4cg .. +3
  int rg = tid >> 4;   // rows row0 + 4rg .. +3
  float4 acc0 = make_float4(0.f, 0.f, 0.f, 0.f);
  float4 acc1 = acc0, acc2 = acc0, acc3 = acc0;
#pragma unroll 4
  for (int k = 0; k < 128; ++k) {
    float4 a = *(const float4*)&sN[k * SN_STRIDE + 4 * rg];  // 4 rows
    float4 w = sW4[k * 16 + cg];                             // 4 cols
    acc0.x = fmaf(a.x, w.x, acc0.x); acc0.y = fmaf(a.x, w.y, acc0.y);
    acc0.z = fmaf(a.x, w.z, acc0.z); acc0.w = fmaf(a.x, w.w, acc0.w);
    acc1.x = fmaf(a.y, w.x, acc1.x); acc1.y = fmaf(a.y, w.y, acc1.y);
    acc1.z = fmaf(a.y, w.z, acc1.z); acc1.w = fmaf(a.y, w.w, acc1.w);
    acc2.x = fmaf(a.z, w.x, acc2.x); acc2.y = fmaf(a.z, w.y, acc2.y);
    acc2.z = fmaf(a.z, w.z, acc2.z); acc2.w = fmaf(a.z, w.w, acc2.w);
    acc3.x = fmaf(a.w, w.x, acc3.x); acc3.y = fmaf(a.w, w.y, acc3.y);
    acc3.z = fmaf(a.w, w.z, acc3.z); acc3.w = fmaf(a.w, w.w, acc3.w);
  }

  // store h + per-thread partial stats (cols col0+4cg..+3)
  float4 s = make_float4(0.f, 0.f, 0.f, 0.f);
  float4 q = s;
  float4 accs[4] = {acc0, acc1, acc2, acc3};
#pragma unroll
  for (int j = 0; j < 4; ++j) {
    int gr = row0 + 4 * rg + j;
    if (gr < N_NODES) {
      ((float4*)h)[(long)gr * 32 + (col0 >> 2) + cg] = accs[j];
      s.x += accs[j].x; s.y += accs[j].y; s.z += accs[j].z; s.w += accs[j].w;
      q.x += accs[j].x * accs[j].x; q.y += accs[j].y * accs[j].y;
      q.z += accs[j].z * accs[j].z; q.w += accs[j].w * accs[j].w;
    }
  }
  __syncthreads();  // sN dead; reuse as stats scratch
  float4* sSum = (float4*)sNbuf;         // [16 rg][16 cg]
  float4* sSq  = ((float4*)sNbuf) + 256;
  sSum[rg * 16 + cg] = s;
  sSq[rg * 16 + cg] = q;
  __syncthreads();
  if (tid < 16) {
    float4 S = make_float4(0.f, 0.f, 0.f, 0.f);
    float4 Q = S;
#pragma unroll
    for (int g = 0; g < 16; ++g) {
      float4 u = sSum[g * 16 + tid];
      float4 v = sSq[g * 16 + tid];
      S.x += u.x; S.y += u.y; S.z += u.z; S.w += u.w;
      Q.x += v.x; Q.y += v.y; Q.z += v.z; Q.w += v.w;
    }
    int cb = col0 + tid * 4;
    unsafeAtomicAdd(colsum + cb + 0, S.x);
    unsafeAtomicAdd(colsum + cb + 1, S.y);
    unsafeAtomicAdd(colsum + cb + 2, S.z);
    unsafeAtomicAdd(colsum + cb + 3, S.w);
    unsafeAtomicAdd(colsumsq + cb + 0, Q.x);
    unsafeAtomicAdd(colsumsq + cb + 1, Q.y);
    unsafeAtomicAdd(colsumsq + cb + 2, Q.z);
    unsafeAtomicAdd(colsumsq + cb + 3, Q.w);
  }
}

// K6: BN (batch stats) + tanh, h (ws) -> out, float4 vectorized.
__global__ __launch_bounds__(256) void bn_tanh(
    const float* __restrict__ h, const float* __restrict__ colsum,
    const float* __restrict__ colsumsq, const float* __restrict__ gamma,
    const float* __restrict__ beta, float* __restrict__ out) {
  const float invN = 1.f / (float)N_NODES;
  const int total4 = N_NODES * 32;
  for (int i = blockIdx.x * 256 + threadIdx.x; i < total4;
       i += gridDim.x * 256) {
    int c4 = i & 31;
    float4 hv = ((const float4*)h)[i];
    float4 S = ((const float4*)colsum)[c4];
    float4 Q = ((const float4*)colsumsq)[c4];
    float4 G = ((const float4*)gamma)[c4];
    float4 B = ((const float4*)beta)[c4];
    float4 o;
    {
      float mu = S.x * invN;
      float var = Q.x * invN - mu * mu;
      o.x = tanhf((hv.x - mu) * rsqrtf(var + BN_EPS) * G.x + B.x);
    }
    {
      float mu = S.y * invN;
      float var = Q.y * invN - mu * mu;
      o.y = tanhf((hv.y - mu) * rsqrtf(var + BN_EPS) * G.y + B.y);
    }
    {
      float mu = S.z * invN;
      float var = Q.z * invN - mu * mu;
      o.z = tanhf((hv.z - mu) * rsqrtf(var + BN_EPS) * G.z + B.z);
    }
    {
      float mu = S.w * invN;
      float var = Q.w * invN - mu * mu;
      o.w = tanhf((hv.w - mu) * rsqrtf(var + BN_EPS) * G.w + B.w);
    }
    ((float4*)out)[i] = o;
  }
}

extern "C" void kernel_launch(void* const* d_in, const int* in_sizes, int n_in,
                              void* d_out, int out_size, void* d_ws, size_t ws_size,
                              hipStream_t stream) {
  const float* ent   = (const float*)d_in[0];
  const float* rel   = (const float*)d_in[1];
  const float* W     = (const float*)d_in[2];
  const float* gamma = (const float*)d_in[3];
  const float* beta  = (const float*)d_in[4];
  const int*   src   = (const int*)d_in[5];
  const int*   dst   = (const int*)d_in[6];
  const int*   rid   = (const int*)d_in[7];
  float* out = (float*)d_out;

  char* ws = (char*)d_ws;
  int* counts      = (int*)(ws + 0);           // 200,000 B
  int* cursor      = (int*)(ws + 200000);      // 200,000 B
  float* colsum    = (float*)(ws + 400000);    // 512 B
  float* colsumsq  = (float*)(ws + 400512);    // 512 B   (zeroed region ends 401,024)
  int* bsum        = (int*)(ws + 401024);      // 1,024 B
  int* bbase       = (int*)(ws + 402048);      // 1,024 B
  int* offsets     = (int*)(ws + 403072);      // 200,004 B -> 603,076
  // einfo (6.4 MB) and h (25.6 MB) share a region: einfo is dead before
  // gemm_stats writes h (strict stream ordering).
  int2* einfo      = (int2*)(ws + 603136);     // 6,400,000 B
  float* h         = (float*)(ws + 603136);    // 25,600,000 B -> 26,203,136 total
  float* scaled    = out;                      // gather result lives in d_out

  // zero: counts, cursor, colsum, colsumsq
  hipMemsetAsync(d_ws, 0, 401024, stream);

  hist<<<(N_EDGES / 4 + 255) / 256, 256, 0, stream>>>(dst, counts);
  scan_blocks<<<SCAN_NB, 256, 0, stream>>>(counts, bsum);
  scan_top<<<1, 64, 0, stream>>>(bsum, bbase, offsets);
  scan_write<<<SCAN_NB, 256, 0, stream>>>(counts, bbase, offsets);
  fill_buckets<<<(N_EDGES / 4 + 255) / 256, 256, 0, stream>>>(src, dst, rid,
                                                              offsets, cursor, einfo);
  gather_fused<<<(N_NODES + 3) / 4, 256, 0, stream>>>(ent, rel, offsets, einfo,
                                                      scaled);
  gemm_stats<<<((N_NODES + GR - 1) / GR) * 2, 256, 0, stream>>>(
      scaled, W, h, colsum, colsumsq);
  bn_tanh<<<2048, 256, 0, stream>>>(h, colsum, colsumsq, gamma, beta, out);
}

// Round 7
// 208.927 us; speedup vs baseline: 1.6227x; 1.2610x over previous
//
#include <hip/hip_runtime.h>
#include <math.h>

#define N_NODES 50000
#define N_EDGES 800000
#define HD 128
#define BN_EPS 1e-5f

#define SCAN_CHUNK 1024
#define SCAN_NB ((N_NODES + SCAN_CHUNK - 1) / SCAN_CHUNK)  // 49

typedef __attribute__((ext_vector_type(8))) short short8;
typedef __attribute__((ext_vector_type(4))) float f32x4;

__device__ __forceinline__ unsigned short f2bf(float f) {
  unsigned u = __float_as_uint(f);
  return (unsigned short)((u + 0x7FFFu + ((u >> 16) & 1u)) >> 16);
}

// K1: dst-degree histogram.
__global__ __launch_bounds__(256) void hist(const int* __restrict__ dst,
                                            int* __restrict__ counts) {
  int i = blockIdx.x * 256 + threadIdx.x;
  if (i >= N_EDGES / 4) return;
  int4 d = ((const int4*)dst)[i];
  atomicAdd(counts + d.x, 1);
  atomicAdd(counts + d.y, 1);
  atomicAdd(counts + d.z, 1);
  atomicAdd(counts + d.w, 1);
}

// K2a/b/c: hierarchical exclusive scan.
__global__ __launch_bounds__(256) void scan_blocks(
    const int* __restrict__ counts, int* __restrict__ bsum) {
  int t = threadIdx.x;
  int idx = blockIdx.x * SCAN_CHUNK + t * 4;
  int s = 0;
  if (idx + 3 < N_NODES) {
    int4 v = *(const int4*)(counts + idx);
    s = v.x + v.y + v.z + v.w;
  } else {
#pragma unroll
    for (int j = 0; j < 4; ++j)
      if (idx + j < N_NODES) s += counts[idx + j];
  }
  __shared__ int ls[256];
  ls[t] = s;
  __syncthreads();
  for (int off = 128; off > 0; off >>= 1) {
    if (t < off) ls[t] += ls[t + off];
    __syncthreads();
  }
  if (t == 0) bsum[blockIdx.x] = ls[0];
}

__global__ __launch_bounds__(64) void scan_top(const int* __restrict__ bsum,
                                               int* __restrict__ bbase,
                                               int* __restrict__ offsets) {
  int t = threadIdx.x;
  int v = (t < SCAN_NB) ? bsum[t] : 0;
  int incl = v;
#pragma unroll
  for (int off = 1; off < 64; off <<= 1) {
    int u = __shfl_up(incl, off, 64);
    if (t >= off) incl += u;
  }
  if (t < SCAN_NB) bbase[t] = incl - v;
  if (t == 63) offsets[N_NODES] = incl;
}

__global__ __launch_bounds__(256) void scan_write(
    const int* __restrict__ counts, const int* __restrict__ bbase,
    int* __restrict__ offsets) {
  int t = threadIdx.x;
  int idx = blockIdx.x * SCAN_CHUNK + t * 4;
  int c[4] = {0, 0, 0, 0};
  if (idx + 3 < N_NODES) {
    int4 v = *(const int4*)(counts + idx);
    c[0] = v.x; c[1] = v.y; c[2] = v.z; c[3] = v.w;
  } else {
#pragma unroll
    for (int j = 0; j < 4; ++j)
      if (idx + j < N_NODES) c[j] = counts[idx + j];
  }
  int s = c[0] + c[1] + c[2] + c[3];
  __shared__ int ls[256];
  ls[t] = s;
  __syncthreads();
  for (int off = 1; off < 256; off <<= 1) {
    int u = (t >= off) ? ls[t - off] : 0;
    __syncthreads();
    ls[t] += u;
    __syncthreads();
  }
  int run = bbase[blockIdx.x] + ls[t] - s;
#pragma unroll
  for (int j = 0; j < 4; ++j) {
    if (idx + j < N_NODES) {
      offsets[idx + j] = run;
      run += c[j];
    }
  }
}

// K3: bucket edges by dst, packing {src, rid} into 8B records.
__global__ __launch_bounds__(256) void fill_buckets(
    const int* __restrict__ src, const int* __restrict__ dst,
    const int* __restrict__ rid, const int* __restrict__ offsets,
    int* __restrict__ cursor, int2* __restrict__ einfo) {
  int i = blockIdx.x * 256 + threadIdx.x;
  if (i >= N_EDGES / 4) return;
  int4 s4 = ((const int4*)src)[i];
  int4 d4 = ((const int4*)dst)[i];
  int4 r4 = ((const int4*)rid)[i];
#pragma unroll
  for (int q = 0; q < 4; ++q) {
    int s = (q == 0) ? s4.x : (q == 1) ? s4.y : (q == 2) ? s4.z : s4.w;
    int d = (q == 0) ? d4.x : (q == 1) ? d4.y : (q == 2) ? d4.z : d4.w;
    int r = (q == 0) ? r4.x : (q == 1) ? r4.y : (q == 2) ? r4.z : r4.w;
    int pos = atomicAdd(cursor + d, 1);
    einfo[offsets[d] + pos] = make_int2(s, r);
  }
}

// K4: fused score + online-softmax + aggregation; writes bf16 rows.
__global__ __launch_bounds__(256) void gather_fused(
    const float* __restrict__ ent, const float* __restrict__ rel,
    const int* __restrict__ offsets, const int2* __restrict__ einfo,
    unsigned short* __restrict__ scaled_bf) {
  int n = blockIdx.x * 4 + (threadIdx.x >> 6);
  if (n >= N_NODES) return;
  int lane = threadIdx.x & 63;
  int s0 = __builtin_amdgcn_readfirstlane(offsets[n]);
  int s1 = __builtin_amdgcn_readfirstlane(offsets[n + 1]);
  float2 b = ((const float2*)(ent + (long)n * HD))[lane];
  float m = -INFINITY, den = 0.f, ax = 0.f, ay = 0.f;
  int s = s0;
  for (; s + 4 <= s1; s += 4) {
    int2 v0 = einfo[s + 0];
    int2 v1 = einfo[s + 1];
    int2 v2 = einfo[s + 2];
    int2 v3 = einfo[s + 3];
    float2 a0 = ((const float2*)(ent + (long)v0.x * HD))[lane];
    float2 c0 = ((const float2*)(rel + (long)v0.y * HD))[lane];
    float2 a1 = ((const float2*)(ent + (long)v1.x * HD))[lane];
    float2 c1 = ((const float2*)(rel + (long)v1.y * HD))[lane];
    float2 a2 = ((const float2*)(ent + (long)v2.x * HD))[lane];
    float2 c2 = ((const float2*)(rel + (long)v2.y * HD))[lane];
    float2 a3 = ((const float2*)(ent + (long)v3.x * HD))[lane];
    float2 c3 = ((const float2*)(rel + (long)v3.y * HD))[lane];
    float cx0 = a0.x * c0.x, cy0 = a0.y * c0.y;
    float cx1 = a1.x * c1.x, cy1 = a1.y * c1.y;
    float cx2 = a2.x * c2.x, cy2 = a2.y * c2.y;
    float cx3 = a3.x * c3.x, cy3 = a3.y * c3.y;
    float p0 = cx0 * b.x + cy0 * b.y;
    float p1 = cx1 * b.x + cy1 * b.y;
    float p2 = cx2 * b.x + cy2 * b.y;
    float p3 = cx3 * b.x + cy3 * b.y;
#pragma unroll
    for (int off = 32; off > 0; off >>= 1) {
      p0 += __shfl_xor(p0, off, 64);
      p1 += __shfl_xor(p1, off, 64);
      p2 += __shfl_xor(p2, off, 64);
      p3 += __shfl_xor(p3, off, 64);
    }
    float pm = fmaxf(fmaxf(fmaxf(p0, p1), fmaxf(p2, p3)), m);
    float f = __expf(m - pm);
    float e0 = __expf(p0 - pm);
    float e1 = __expf(p1 - pm);
    float e2 = __expf(p2 - pm);
    float e3 = __expf(p3 - pm);
    den = den * f + ((e0 + e1) + (e2 + e3));
    ax = ax * f + cx0 * e0 + cx1 * e1 + cx2 * e2 + cx3 * e3;
    ay = ay * f + cy0 * e0 + cy1 * e1 + cy2 * e2 + cy3 * e3;
    m = pm;
  }
  for (; s < s1; ++s) {
    int2 v = einfo[s];
    float2 a = ((const float2*)(ent + (long)v.x * HD))[lane];
    float2 c = ((const float2*)(rel + (long)v.y * HD))[lane];
    float cx = a.x * c.x, cy = a.y * c.y;
    float p = cx * b.x + cy * b.y;
#pragma unroll
    for (int off = 32; off > 0; off >>= 1) p += __shfl_xor(p, off, 64);
    float mn = fmaxf(m, p);
    float f = __expf(m - mn);
    float e = __expf(p - mn);
    den = den * f + e;
    ax = ax * f + cx * e;
    ay = ay * f + cy * e;
    m = mn;
  }
  float inv = den > 0.f ? 1.f / den : 0.f;
  ushort2 o;
  o.x = f2bf(ax * inv);
  o.y = f2bf(ay * inv);
  ((ushort2*)(scaled_bf + (long)n * HD))[lane] = o;
}

// K_pre: W[k][col] f32 -> Wt[col][k] bf16 (LDS transpose, single block).
__global__ __launch_bounds__(256) void conv_w(const float* __restrict__ W,
                                              unsigned short* __restrict__ Wt) {
  __shared__ float sT[128 * 132];
  int tid = threadIdx.x;
  for (int i = tid; i < 4096; i += 256) {  // 4096 float4 = 128x128
    float4 v = ((const float4*)W)[i];
    int k = i >> 5, c = (i & 31) * 4;
    sT[k * 132 + c + 0] = v.x;
    sT[k * 132 + c + 1] = v.y;
    sT[k * 132 + c + 2] = v.z;
    sT[k * 132 + c + 3] = v.w;
  }
  __syncthreads();
  for (int o = tid; o < 128 * 128; o += 256) {
    int col = o >> 7, k = o & 127;
    Wt[o] = f2bf(sT[k * 132 + col]);
  }
}

// K5: h = scaled_bf @ W via MFMA bf16, stats fused.
// Block: 256 thr = 4 waves, 64 rows, full N=128, K=128.
// Per wave: 16 rows; 4 kt x 8 n-tiles of mfma_f32_16x16x32_bf16.
// A: row=lane&15, k=(lane>>4)*8+i.  B: col=lane&15, k=(lane>>4)*8+i.
// D: col=lane&15, row=(lane>>4)*4+r  (m89-verified mapping).
__global__ __launch_bounds__(256) void gemm_mfma(
    const unsigned short* __restrict__ scaled_bf,
    const unsigned short* __restrict__ Wt, float* __restrict__ h,
    float* __restrict__ colsum, float* __restrict__ colsumsq) {
  __shared__ unsigned short sW[128 * 136];   // [col][k], pad->stride 136 bf16
  __shared__ unsigned short sA[4][16][144];  // [wave][row][k], stride 144 bf16
  int tid = threadIdx.x;
  int row0 = blockIdx.x * 64;

  // stage Wt (32KB payload) -> sW with stride 136
  for (int i = tid; i < 2048; i += 256) {
    int col = i >> 4, c8 = i & 15;
    *(int4*)&sW[col * 136 + c8 * 8] = ((const int4*)Wt)[i];
  }
  // stage 64 rows of scaled_bf -> sA
  for (int i = tid; i < 1024; i += 256) {
    int r = i >> 4, c8 = i & 15;
    int gr = row0 + r;
    int4 v = make_int4(0, 0, 0, 0);
    if (gr < N_NODES) v = ((const int4*)(scaled_bf + (long)gr * HD))[c8];
    *(int4*)&sA[r >> 4][r & 15][c8 * 8] = v;
  }
  __syncthreads();

  int w = tid >> 6, lane = tid & 63;
  int lrow = lane & 15, lk = lane >> 4;
  f32x4 acc[8];
#pragma unroll
  for (int n = 0; n < 8; ++n) acc[n] = (f32x4){0.f, 0.f, 0.f, 0.f};

#pragma unroll
  for (int kt = 0; kt < 4; ++kt) {
    short8 aF = *(const short8*)&sA[w][lrow][kt * 32 + lk * 8];
#pragma unroll
    for (int n = 0; n < 8; ++n) {
      short8 bF = *(const short8*)&sW[(n * 16 + lrow) * 136 + kt * 32 + lk * 8];
      acc[n] = __builtin_amdgcn_mfma_f32_16x16x32_bf16(aF, bF, acc[n], 0, 0, 0);
    }
  }

  // store h + per-lane partial stats
  float s[8], q[8];
#pragma unroll
  for (int n = 0; n < 8; ++n) {
    int col = n * 16 + lrow;
    s[n] = 0.f;
    q[n] = 0.f;
#pragma unroll
    for (int r = 0; r < 4; ++r) {
      float v = acc[n][r];
      int grow = row0 + w * 16 + lk * 4 + r;
      if (grow < N_NODES) h[(long)grow * HD + col] = v;
      s[n] += v;          // rows >= N contribute 0 (zero-staged A)
      q[n] += v * v;
    }
    // reduce over lk groups (lane bits 4,5); col (lane&15) preserved
    s[n] += __shfl_xor(s[n], 16, 64);
    s[n] += __shfl_xor(s[n], 32, 64);
    q[n] += __shfl_xor(q[n], 16, 64);
    q[n] += __shfl_xor(q[n], 32, 64);
  }

  __syncthreads();  // sA dead; reuse as stats scratch
  float* sStat = (float*)&sA[0][0][0];  // [256]: 0..127 sum, 128..255 sumsq
  sStat[tid] = 0.f;
  __syncthreads();
  if (lane < 16) {
#pragma unroll
    for (int n = 0; n < 8; ++n) {
      atomicAdd(&sStat[n * 16 + lrow], s[n]);
      atomicAdd(&sStat[128 + n * 16 + lrow], q[n]);
    }
  }
  __syncthreads();
  if (tid < 128) {
    unsafeAtomicAdd(colsum + tid, sStat[tid]);
    unsafeAtomicAdd(colsumsq + tid, sStat[128 + tid]);
  }
}

// K6: BN (batch stats) + tanh, in place on h (= d_out).
__global__ __launch_bounds__(256) void bn_tanh(
    float* __restrict__ h, const float* __restrict__ colsum,
    const float* __restrict__ colsumsq, const float* __restrict__ gamma,
    const float* __restrict__ beta) {
  const float invN = 1.f / (float)N_NODES;
  const int total4 = N_NODES * 32;
  for (int i = blockIdx.x * 256 + threadIdx.x; i < total4;
       i += gridDim.x * 256) {
    int c4 = i & 31;
    float4 hv = ((float4*)h)[i];
    float4 S = ((const float4*)colsum)[c4];
    float4 Q = ((const float4*)colsumsq)[c4];
    float4 G = ((const float4*)gamma)[c4];
    float4 B = ((const float4*)beta)[c4];
    float4 o;
    {
      float mu = S.x * invN, var = Q.x * invN - mu * mu;
      o.x = tanhf((hv.x - mu) * rsqrtf(var + BN_EPS) * G.x + B.x);
    }
    {
      float mu = S.y * invN, var = Q.y * invN - mu * mu;
      o.y = tanhf((hv.y - mu) * rsqrtf(var + BN_EPS) * G.y + B.y);
    }
    {
      float mu = S.z * invN, var = Q.z * invN - mu * mu;
      o.z = tanhf((hv.z - mu) * rsqrtf(var + BN_EPS) * G.z + B.z);
    }
    {
      float mu = S.w * invN, var = Q.w * invN - mu * mu;
      o.w = tanhf((hv.w - mu) * rsqrtf(var + BN_EPS) * G.w + B.w);
    }
    ((float4*)h)[i] = o;
  }
}

extern "C" void kernel_launch(void* const* d_in, const int* in_sizes, int n_in,
                              void* d_out, int out_size, void* d_ws, size_t ws_size,
                              hipStream_t stream) {
  const float* ent   = (const float*)d_in[0];
  const float* rel   = (const float*)d_in[1];
  const float* W     = (const float*)d_in[2];
  const float* gamma = (const float*)d_in[3];
  const float* beta  = (const float*)d_in[4];
  const int*   src   = (const int*)d_in[5];
  const int*   dst   = (const int*)d_in[6];
  const int*   rid   = (const int*)d_in[7];
  float* out = (float*)d_out;

  char* ws = (char*)d_ws;
  int* counts      = (int*)(ws + 0);           // 200,000 B
  int* cursor      = (int*)(ws + 200000);      // 200,000 B
  float* colsum    = (float*)(ws + 400000);    // 512 B
  float* colsumsq  = (float*)(ws + 400512);    // 512 B  (zeroed region ends 401,024)
  int* bsum        = (int*)(ws + 401024);      // 1,024 B
  int* bbase       = (int*)(ws + 402048);      // 1,024 B
  int* offsets     = (int*)(ws + 403072);      // 200,004 B -> 603,076
  unsigned short* Wt        = (unsigned short*)(ws + 603136);    // 32,768 B
  int2* einfo               = (int2*)(ws + 635904);              // 6,400,000 B
  unsigned short* scaled_bf = (unsigned short*)(ws + 7035904);   // 12,800,000 B
  // total ws: 19,835,904 B;  h lives in d_out (bn_tanh in place)

  hipMemsetAsync(d_ws, 0, 401024, stream);

  hist<<<(N_EDGES / 4 + 255) / 256, 256, 0, stream>>>(dst, counts);
  scan_blocks<<<SCAN_NB, 256, 0, stream>>>(counts, bsum);
  scan_top<<<1, 64, 0, stream>>>(bsum, bbase, offsets);
  scan_write<<<SCAN_NB, 256, 0, stream>>>(counts, bbase, offsets);
  conv_w<<<1, 256, 0, stream>>>(W, Wt);
  fill_buckets<<<(N_EDGES / 4 + 255) / 256, 256, 0, stream>>>(src, dst, rid,
                                                              offsets, cursor, einfo);
  gather_fused<<<(N_NODES + 3) / 4, 256, 0, stream>>>(ent, rel, offsets, einfo,
                                                      scaled_bf);
  gemm_mfma<<<(N_NODES + 63) / 64, 256, 0, stream>>>(scaled_bf, Wt, out,
                                                     colsum, colsumsq);
  bn_tanh<<<2048, 256, 0, stream>>>(out, colsum, colsumsq, gamma, beta);
}

// Round 8
// 204.269 us; speedup vs baseline: 1.6597x; 1.0228x over previous
//
#include <hip/hip_runtime.h>
#include <math.h>

#define N_NODES 50000
#define N_EDGES 800000
#define HD 128
#define BN_EPS 1e-5f

#define SCAN_CHUNK 1024
#define SCAN_NB ((N_NODES + SCAN_CHUNK - 1) / SCAN_CHUNK)  // 49

typedef __attribute__((ext_vector_type(8))) short short8;
typedef __attribute__((ext_vector_type(4))) float f32x4;

__device__ __forceinline__ unsigned short f2bf(float f) {
  unsigned u = __float_as_uint(f);
  return (unsigned short)((u + 0x7FFFu + ((u >> 16) & 1u)) >> 16);
}

// K1: dst-degree histogram.
__global__ __launch_bounds__(256) void hist(const int* __restrict__ dst,
                                            int* __restrict__ counts) {
  int i = blockIdx.x * 256 + threadIdx.x;
  if (i >= N_EDGES / 4) return;
  int4 d = ((const int4*)dst)[i];
  atomicAdd(counts + d.x, 1);
  atomicAdd(counts + d.y, 1);
  atomicAdd(counts + d.z, 1);
  atomicAdd(counts + d.w, 1);
}

// K2a/b/c: hierarchical exclusive scan.
__global__ __launch_bounds__(256) void scan_blocks(
    const int* __restrict__ counts, int* __restrict__ bsum) {
  int t = threadIdx.x;
  int idx = blockIdx.x * SCAN_CHUNK + t * 4;
  int s = 0;
  if (idx + 3 < N_NODES) {
    int4 v = *(const int4*)(counts + idx);
    s = v.x + v.y + v.z + v.w;
  } else {
#pragma unroll
    for (int j = 0; j < 4; ++j)
      if (idx + j < N_NODES) s += counts[idx + j];
  }
  __shared__ int ls[256];
  ls[t] = s;
  __syncthreads();
  for (int off = 128; off > 0; off >>= 1) {
    if (t < off) ls[t] += ls[t + off];
    __syncthreads();
  }
  if (t == 0) bsum[blockIdx.x] = ls[0];
}

__global__ __launch_bounds__(64) void scan_top(const int* __restrict__ bsum,
                                               int* __restrict__ bbase,
                                               int* __restrict__ offsets) {
  int t = threadIdx.x;
  int v = (t < SCAN_NB) ? bsum[t] : 0;
  int incl = v;
#pragma unroll
  for (int off = 1; off < 64; off <<= 1) {
    int u = __shfl_up(incl, off, 64);
    if (t >= off) incl += u;
  }
  if (t < SCAN_NB) bbase[t] = incl - v;
  if (t == 63) offsets[N_NODES] = incl;
}

__global__ __launch_bounds__(256) void scan_write(
    const int* __restrict__ counts, const int* __restrict__ bbase,
    int* __restrict__ offsets) {
  int t = threadIdx.x;
  int idx = blockIdx.x * SCAN_CHUNK + t * 4;
  int c[4] = {0, 0, 0, 0};
  if (idx + 3 < N_NODES) {
    int4 v = *(const int4*)(counts + idx);
    c[0] = v.x; c[1] = v.y; c[2] = v.z; c[3] = v.w;
  } else {
#pragma unroll
    for (int j = 0; j < 4; ++j)
      if (idx + j < N_NODES) c[j] = counts[idx + j];
  }
  int s = c[0] + c[1] + c[2] + c[3];
  __shared__ int ls[256];
  ls[t] = s;
  __syncthreads();
  for (int off = 1; off < 256; off <<= 1) {
    int u = (t >= off) ? ls[t - off] : 0;
    __syncthreads();
    ls[t] += u;
    __syncthreads();
  }
  int run = bbase[blockIdx.x] + ls[t] - s;
#pragma unroll
  for (int j = 0; j < 4; ++j) {
    if (idx + j < N_NODES) {
      offsets[idx + j] = run;
      run += c[j];
    }
  }
}

// K3: bucket edges by dst, packing {src, rid} into 8B records.
__global__ __launch_bounds__(256) void fill_buckets(
    const int* __restrict__ src, const int* __restrict__ dst,
    const int* __restrict__ rid, const int* __restrict__ offsets,
    int* __restrict__ cursor, int2* __restrict__ einfo) {
  int i = blockIdx.x * 256 + threadIdx.x;
  if (i >= N_EDGES / 4) return;
  int4 s4 = ((const int4*)src)[i];
  int4 d4 = ((const int4*)dst)[i];
  int4 r4 = ((const int4*)rid)[i];
#pragma unroll
  for (int q = 0; q < 4; ++q) {
    int s = (q == 0) ? s4.x : (q == 1) ? s4.y : (q == 2) ? s4.z : s4.w;
    int d = (q == 0) ? d4.x : (q == 1) ? d4.y : (q == 2) ? d4.z : d4.w;
    int r = (q == 0) ? r4.x : (q == 1) ? r4.y : (q == 2) ? r4.z : r4.w;
    int pos = atomicAdd(cursor + d, 1);
    einfo[offsets[d] + pos] = make_int2(s, r);
  }
}

// K4: fused score + online-softmax + aggregation; writes bf16 rows.
// One wave per dst node, split into two 32-lane halves; each half processes
// its own edge stream (float4/lane), merged once at the end.
__global__ __launch_bounds__(256) void gather_fused(
    const float* __restrict__ ent, const float* __restrict__ rel,
    const int* __restrict__ offsets, const int2* __restrict__ einfo,
    unsigned short* __restrict__ scaled_bf) {
  int n = blockIdx.x * 4 + (threadIdx.x >> 6);
  if (n >= N_NODES) return;
  int lane = threadIdx.x & 63;
  int half = lane >> 5;
  int l32 = lane & 31;
  int s0 = __builtin_amdgcn_readfirstlane(offsets[n]);
  int s1 = __builtin_amdgcn_readfirstlane(offsets[n + 1]);
  float4 b = ((const float4*)(ent + (long)n * HD))[l32];
  const int2* ei = einfo + half;

  float m = -INFINITY, den = 0.f;
  float4 acc = make_float4(0.f, 0.f, 0.f, 0.f);
  int s = s0;
  // 4 edges per iteration (2 per half)
  for (; s + 4 <= s1; s += 4) {
    int2 v0 = ei[s];
    int2 v1 = ei[s + 2];
    float4 a0 = ((const float4*)(ent + (long)v0.x * HD))[l32];
    float4 c0 = ((const float4*)(rel + (long)v0.y * HD))[l32];
    float4 a1 = ((const float4*)(ent + (long)v1.x * HD))[l32];
    float4 c1 = ((const float4*)(rel + (long)v1.y * HD))[l32];
    float4 q0, q1;
    q0.x = a0.x * c0.x; q0.y = a0.y * c0.y; q0.z = a0.z * c0.z; q0.w = a0.w * c0.w;
    q1.x = a1.x * c1.x; q1.y = a1.y * c1.y; q1.z = a1.z * c1.z; q1.w = a1.w * c1.w;
    float p0 = q0.x * b.x + q0.y * b.y + q0.z * b.z + q0.w * b.w;
    float p1 = q1.x * b.x + q1.y * b.y + q1.z * b.z + q1.w * b.w;
#pragma unroll
    for (int off = 16; off > 0; off >>= 1) {  // reduce within each 32-lane half
      p0 += __shfl_xor(p0, off, 64);
      p1 += __shfl_xor(p1, off, 64);
    }
    float pm = fmaxf(fmaxf(p0, p1), m);
    float f = __expf(m - pm);  // m=-inf, pm finite -> 0 (no NaN)
    float e0 = __expf(p0 - pm);
    float e1 = __expf(p1 - pm);
    den = den * f + (e0 + e1);
    acc.x = fmaf(acc.x, f, q0.x * e0 + q1.x * e1);
    acc.y = fmaf(acc.y, f, q0.y * e0 + q1.y * e1);
    acc.z = fmaf(acc.z, f, q0.z * e0 + q1.z * e1);
    acc.w = fmaf(acc.w, f, q0.w * e0 + q1.w * e1);
    m = pm;
  }
  // 2-edge step (1 per half)
  for (; s + 2 <= s1; s += 2) {
    int2 v = ei[s];
    float4 a = ((const float4*)(ent + (long)v.x * HD))[l32];
    float4 c = ((const float4*)(rel + (long)v.y * HD))[l32];
    float4 q;
    q.x = a.x * c.x; q.y = a.y * c.y; q.z = a.z * c.z; q.w = a.w * c.w;
    float p = q.x * b.x + q.y * b.y + q.z * b.z + q.w * b.w;
#pragma unroll
    for (int off = 16; off > 0; off >>= 1) p += __shfl_xor(p, off, 64);
    float pm = fmaxf(p, m);
    float f = __expf(m - pm);
    float e = __expf(p - pm);
    den = den * f + e;
    acc.x = fmaf(acc.x, f, q.x * e);
    acc.y = fmaf(acc.y, f, q.y * e);
    acc.z = fmaf(acc.z, f, q.z * e);
    acc.w = fmaf(acc.w, f, q.w * e);
    m = pm;
  }
  // odd final edge: both halves compute it; half 1 contributes zero.
  if (s < s1) {
    int2 v = einfo[s];
    float4 a = ((const float4*)(ent + (long)v.x * HD))[l32];
    float4 c = ((const float4*)(rel + (long)v.y * HD))[l32];
    float4 q;
    q.x = a.x * c.x; q.y = a.y * c.y; q.z = a.z * c.z; q.w = a.w * c.w;
    float p = q.x * b.x + q.y * b.y + q.z * b.z + q.w * b.w;
#pragma unroll
    for (int off = 16; off > 0; off >>= 1) p += __shfl_xor(p, off, 64);
    float pn = half ? -INFINITY : p;
    float pm = fmaxf(m, pn);
    float f = (m == -INFINITY) ? 0.f : __expf(m - pm);
    float e = (pn == -INFINITY) ? 0.f : __expf(pn - pm);
    den = den * f + e;
    acc.x = fmaf(acc.x, f, q.x * e);
    acc.y = fmaf(acc.y, f, q.y * e);
    acc.z = fmaf(acc.z, f, q.z * e);
    acc.w = fmaf(acc.w, f, q.w * e);
    m = pm;
  }
  // merge the two halves
  float mo = __shfl_xor(m, 32, 64);
  float deno = __shfl_xor(den, 32, 64);
  float4 acco;
  acco.x = __shfl_xor(acc.x, 32, 64);
  acco.y = __shfl_xor(acc.y, 32, 64);
  acco.z = __shfl_xor(acc.z, 32, 64);
  acco.w = __shfl_xor(acc.w, 32, 64);
  float mm = fmaxf(m, mo);
  float fs = (mm == -INFINITY) ? 0.f : __expf(m - mm);
  float fo = (mm == -INFINITY) ? 0.f : __expf(mo - mm);
  float dtot = den * fs + deno * fo;
  float inv = dtot > 0.f ? 1.f / dtot : 0.f;
  if (half == 0) {
    ushort4 o;
    o.x = f2bf((acc.x * fs + acco.x * fo) * inv);
    o.y = f2bf((acc.y * fs + acco.y * fo) * inv);
    o.z = f2bf((acc.z * fs + acco.z * fo) * inv);
    o.w = f2bf((acc.w * fs + acco.w * fo) * inv);
    ((ushort4*)(scaled_bf + (long)n * HD))[l32] = o;
  }
}

// K_pre: W[k][col] f32 -> Wt[col][k] bf16 (LDS transpose, single block).
__global__ __launch_bounds__(256) void conv_w(const float* __restrict__ W,
                                              unsigned short* __restrict__ Wt) {
  __shared__ float sT[128 * 132];
  int tid = threadIdx.x;
  for (int i = tid; i < 4096; i += 256) {
    float4 v = ((const float4*)W)[i];
    int k = i >> 5, c = (i & 31) * 4;
    sT[k * 132 + c + 0] = v.x;
    sT[k * 132 + c + 1] = v.y;
    sT[k * 132 + c + 2] = v.z;
    sT[k * 132 + c + 3] = v.w;
  }
  __syncthreads();
  for (int o = tid; o < 128 * 128; o += 256) {
    int col = o >> 7, k = o & 127;
    Wt[o] = f2bf(sT[k * 132 + col]);
  }
}

// K5: h = scaled_bf @ W via MFMA bf16, stats fused.
__global__ __launch_bounds__(256) void gemm_mfma(
    const unsigned short* __restrict__ scaled_bf,
    const unsigned short* __restrict__ Wt, float* __restrict__ h,
    float* __restrict__ colsum, float* __restrict__ colsumsq) {
  __shared__ unsigned short sW[128 * 136];   // [col][k], pad->stride 136 bf16
  __shared__ unsigned short sA[4][16][144];  // [wave][row][k], stride 144 bf16
  int tid = threadIdx.x;
  int row0 = blockIdx.x * 64;

  for (int i = tid; i < 2048; i += 256) {
    int col = i >> 4, c8 = i & 15;
    *(int4*)&sW[col * 136 + c8 * 8] = ((const int4*)Wt)[i];
  }
  for (int i = tid; i < 1024; i += 256) {
    int r = i >> 4, c8 = i & 15;
    int gr = row0 + r;
    int4 v = make_int4(0, 0, 0, 0);
    if (gr < N_NODES) v = ((const int4*)(scaled_bf + (long)gr * HD))[c8];
    *(int4*)&sA[r >> 4][r & 15][c8 * 8] = v;
  }
  __syncthreads();

  int w = tid >> 6, lane = tid & 63;
  int lrow = lane & 15, lk = lane >> 4;
  f32x4 acc[8];
#pragma unroll
  for (int n = 0; n < 8; ++n) acc[n] = (f32x4){0.f, 0.f, 0.f, 0.f};

#pragma unroll
  for (int kt = 0; kt < 4; ++kt) {
    short8 aF = *(const short8*)&sA[w][lrow][kt * 32 + lk * 8];
#pragma unroll
    for (int n = 0; n < 8; ++n) {
      short8 bF = *(const short8*)&sW[(n * 16 + lrow) * 136 + kt * 32 + lk * 8];
      acc[n] = __builtin_amdgcn_mfma_f32_16x16x32_bf16(aF, bF, acc[n], 0, 0, 0);
    }
  }

  float s[8], q[8];
#pragma unroll
  for (int n = 0; n < 8; ++n) {
    int col = n * 16 + lrow;
    s[n] = 0.f;
    q[n] = 0.f;
#pragma unroll
    for (int r = 0; r < 4; ++r) {
      float v = acc[n][r];
      int grow = row0 + w * 16 + lk * 4 + r;
      if (grow < N_NODES) h[(long)grow * HD + col] = v;
      s[n] += v;
      q[n] += v * v;
    }
    s[n] += __shfl_xor(s[n], 16, 64);
    s[n] += __shfl_xor(s[n], 32, 64);
    q[n] += __shfl_xor(q[n], 16, 64);
    q[n] += __shfl_xor(q[n], 32, 64);
  }

  __syncthreads();
  float* sStat = (float*)&sA[0][0][0];
  sStat[tid] = 0.f;
  __syncthreads();
  if (lane < 16) {
#pragma unroll
    for (int n = 0; n < 8; ++n) {
      atomicAdd(&sStat[n * 16 + lrow], s[n]);
      atomicAdd(&sStat[128 + n * 16 + lrow], q[n]);
    }
  }
  __syncthreads();
  if (tid < 128) {
    unsafeAtomicAdd(colsum + tid, sStat[tid]);
    unsafeAtomicAdd(colsumsq + tid, sStat[128 + tid]);
  }
}

// K6: BN (batch stats) + tanh, in place on h (= d_out).
__global__ __launch_bounds__(256) void bn_tanh(
    float* __restrict__ h, const float* __restrict__ colsum,
    const float* __restrict__ colsumsq, const float* __restrict__ gamma,
    const float* __restrict__ beta) {
  const float invN = 1.f / (float)N_NODES;
  const int total4 = N_NODES * 32;
  for (int i = blockIdx.x * 256 + threadIdx.x; i < total4;
       i += gridDim.x * 256) {
    int c4 = i & 31;
    float4 hv = ((float4*)h)[i];
    float4 S = ((const float4*)colsum)[c4];
    float4 Q = ((const float4*)colsumsq)[c4];
    float4 G = ((const float4*)gamma)[c4];
    float4 B = ((const float4*)beta)[c4];
    float4 o;
    {
      float mu = S.x * invN, var = Q.x * invN - mu * mu;
      o.x = tanhf((hv.x - mu) * rsqrtf(var + BN_EPS) * G.x + B.x);
    }
    {
      float mu = S.y * invN, var = Q.y * invN - mu * mu;
      o.y = tanhf((hv.y - mu) * rsqrtf(var + BN_EPS) * G.y + B.y);
    }
    {
      float mu = S.z * invN, var = Q.z * invN - mu * mu;
      o.z = tanhf((hv.z - mu) * rsqrtf(var + BN_EPS) * G.z + B.z);
    }
    {
      float mu = S.w * invN, var = Q.w * invN - mu * mu;
      o.w = tanhf((hv.w - mu) * rsqrtf(var + BN_EPS) * G.w + B.w);
    }
    ((float4*)h)[i] = o;
  }
}

extern "C" void kernel_launch(void* const* d_in, const int* in_sizes, int n_in,
                              void* d_out, int out_size, void* d_ws, size_t ws_size,
                              hipStream_t stream) {
  const float* ent   = (const float*)d_in[0];
  const float* rel   = (const float*)d_in[1];
  const float* W     = (const float*)d_in[2];
  const float* gamma = (const float*)d_in[3];
  const float* beta  = (const float*)d_in[4];
  const int*   src   = (const int*)d_in[5];
  const int*   dst   = (const int*)d_in[6];
  const int*   rid   = (const int*)d_in[7];
  float* out = (float*)d_out;

  char* ws = (char*)d_ws;
  int* counts      = (int*)(ws + 0);           // 200,000 B
  int* cursor      = (int*)(ws + 200000);      // 200,000 B
  float* colsum    = (float*)(ws + 400000);    // 512 B
  float* colsumsq  = (float*)(ws + 400512);    // 512 B  (zeroed region ends 401,024)
  int* bsum        = (int*)(ws + 401024);      // 1,024 B
  int* bbase       = (int*)(ws + 402048);      // 1,024 B
  int* offsets     = (int*)(ws + 403072);      // 200,004 B -> 603,076
  unsigned short* Wt        = (unsigned short*)(ws + 603136);    // 32,768 B
  int2* einfo               = (int2*)(ws + 635904);              // 6,400,000 B
  unsigned short* scaled_bf = (unsigned short*)(ws + 7035904);   // 12,800,000 B
  // total ws: 19,835,904 B;  h lives in d_out (bn_tanh in place)

  hipMemsetAsync(d_ws, 0, 401024, stream);

  hist<<<(N_EDGES / 4 + 255) / 256, 256, 0, stream>>>(dst, counts);
  scan_blocks<<<SCAN_NB, 256, 0, stream>>>(counts, bsum);
  scan_top<<<1, 64, 0, stream>>>(bsum, bbase, offsets);
  scan_write<<<SCAN_NB, 256, 0, stream>>>(counts, bbase, offsets);
  conv_w<<<1, 256, 0, stream>>>(W, Wt);
  fill_buckets<<<(N_EDGES / 4 + 255) / 256, 256, 0, stream>>>(src, dst, rid,
                                                              offsets, cursor, einfo);
  gather_fused<<<(N_NODES + 3) / 4, 256, 0, stream>>>(ent, rel, offsets, einfo,
                                                      scaled_bf);
  gemm_mfma<<<(N_NODES + 63) / 64, 256, 0, stream>>>(scaled_bf, Wt, out,
                                                     colsum, colsumsq);
  bn_tanh<<<2048, 256, 0, stream>>>(out, colsum, colsumsq, gamma, beta);
}

// Round 9
// 202.779 us; speedup vs baseline: 1.6719x; 1.0074x over previous
//
#include <hip/hip_runtime.h>
#include <hip/hip_fp16.h>
#include <math.h>

#define N_NODES 50000
#define N_EDGES 800000
#define HD 128
#define BN_EPS 1e-5f

#define SCAN_CHUNK 1024
#define SCAN_NB ((N_NODES + SCAN_CHUNK - 1) / SCAN_CHUNK)  // 49

typedef __attribute__((ext_vector_type(8))) _Float16 half8;
typedef __attribute__((ext_vector_type(4))) float f32x4;

__device__ __forceinline__ unsigned short f2h(float f) {
  __half h = __float2half(f);
  return __half_as_ushort(h);
}

// K1: dst-degree histogram.
__global__ __launch_bounds__(256) void hist(const int* __restrict__ dst,
                                            int* __restrict__ counts) {
  int i = blockIdx.x * 256 + threadIdx.x;
  if (i >= N_EDGES / 4) return;
  int4 d = ((const int4*)dst)[i];
  atomicAdd(counts + d.x, 1);
  atomicAdd(counts + d.y, 1);
  atomicAdd(counts + d.z, 1);
  atomicAdd(counts + d.w, 1);
}

// K2a/b/c: hierarchical exclusive scan.
__global__ __launch_bounds__(256) void scan_blocks(
    const int* __restrict__ counts, int* __restrict__ bsum) {
  int t = threadIdx.x;
  int idx = blockIdx.x * SCAN_CHUNK + t * 4;
  int s = 0;
  if (idx + 3 < N_NODES) {
    int4 v = *(const int4*)(counts + idx);
    s = v.x + v.y + v.z + v.w;
  } else {
#pragma unroll
    for (int j = 0; j < 4; ++j)
      if (idx + j < N_NODES) s += counts[idx + j];
  }
  __shared__ int ls[256];
  ls[t] = s;
  __syncthreads();
  for (int off = 128; off > 0; off >>= 1) {
    if (t < off) ls[t] += ls[t + off];
    __syncthreads();
  }
  if (t == 0) bsum[blockIdx.x] = ls[0];
}

__global__ __launch_bounds__(64) void scan_top(const int* __restrict__ bsum,
                                               int* __restrict__ bbase,
                                               int* __restrict__ offsets) {
  int t = threadIdx.x;
  int v = (t < SCAN_NB) ? bsum[t] : 0;
  int incl = v;
#pragma unroll
  for (int off = 1; off < 64; off <<= 1) {
    int u = __shfl_up(incl, off, 64);
    if (t >= off) incl += u;
  }
  if (t < SCAN_NB) bbase[t] = incl - v;
  if (t == 63) offsets[N_NODES] = incl;
}

__global__ __launch_bounds__(256) void scan_write(
    const int* __restrict__ counts, const int* __restrict__ bbase,
    int* __restrict__ offsets) {
  int t = threadIdx.x;
  int idx = blockIdx.x * SCAN_CHUNK + t * 4;
  int c[4] = {0, 0, 0, 0};
  if (idx + 3 < N_NODES) {
    int4 v = *(const int4*)(counts + idx);
    c[0] = v.x; c[1] = v.y; c[2] = v.z; c[3] = v.w;
  } else {
#pragma unroll
    for (int j = 0; j < 4; ++j)
      if (idx + j < N_NODES) c[j] = counts[idx + j];
  }
  int s = c[0] + c[1] + c[2] + c[3];
  __shared__ int ls[256];
  ls[t] = s;
  __syncthreads();
  for (int off = 1; off < 256; off <<= 1) {
    int u = (t >= off) ? ls[t - off] : 0;
    __syncthreads();
    ls[t] += u;
    __syncthreads();
  }
  int run = bbase[blockIdx.x] + ls[t] - s;
#pragma unroll
  for (int j = 0; j < 4; ++j) {
    if (idx + j < N_NODES) {
      offsets[idx + j] = run;
      run += c[j];
    }
  }
}

// K3: bucket edges by dst.  Record packed to 4B: src | (rid<<16)
// (src < 65536, rid < 256).
__global__ __launch_bounds__(256) void fill_buckets(
    const int* __restrict__ src, const int* __restrict__ dst,
    const int* __restrict__ rid, const int* __restrict__ offsets,
    int* __restrict__ cursor, int* __restrict__ einfo) {
  int i = blockIdx.x * 256 + threadIdx.x;
  if (i >= N_EDGES / 4) return;
  int4 s4 = ((const int4*)src)[i];
  int4 d4 = ((const int4*)dst)[i];
  int4 r4 = ((const int4*)rid)[i];
#pragma unroll
  for (int q = 0; q < 4; ++q) {
    int s = (q == 0) ? s4.x : (q == 1) ? s4.y : (q == 2) ? s4.z : s4.w;
    int d = (q == 0) ? d4.x : (q == 1) ? d4.y : (q == 2) ? d4.z : d4.w;
    int r = (q == 0) ? r4.x : (q == 1) ? r4.y : (q == 2) ? r4.z : r4.w;
    int pos = atomicAdd(cursor + d, 1);
    einfo[offsets[d] + pos] = s | (r << 16);
  }
}

// K4: fused score + online-softmax + aggregation; writes fp16 rows.
// One wave per dst node, two 32-lane halves with independent online-softmax
// state; 8 edges per unrolled iteration (4 per half) for deep MLP.
__global__ __launch_bounds__(256) void gather_fused(
    const float* __restrict__ ent, const float* __restrict__ rel,
    const int* __restrict__ offsets, const int* __restrict__ einfo,
    unsigned short* __restrict__ scaled_h) {
  int n = blockIdx.x * 4 + (threadIdx.x >> 6);
  if (n >= N_NODES) return;
  int lane = threadIdx.x & 63;
  int half = lane >> 5;
  int l32 = lane & 31;
  int s0 = __builtin_amdgcn_readfirstlane(offsets[n]);
  int s1 = __builtin_amdgcn_readfirstlane(offsets[n + 1]);
  float4 b = ((const float4*)(ent + (long)n * HD))[l32];
  const int* ei = einfo + half;
  const float4* ent4 = (const float4*)ent;
  const float4* rel4 = (const float4*)rel;

  float m = -INFINITY, den = 0.f;
  float4 acc = make_float4(0.f, 0.f, 0.f, 0.f);
  int s = s0;
  // 8 edges per iteration (4 per half): 16 row-loads in flight.
  for (; s + 8 <= s1; s += 8) {
    int w0 = ei[s + 0];
    int w1 = ei[s + 2];
    int w2 = ei[s + 4];
    int w3 = ei[s + 6];
    float4 a0 = ent4[(long)(w0 & 0xFFFF) * 32 + l32];
    float4 c0 = rel4[(w0 >> 16) * 32 + l32];
    float4 a1 = ent4[(long)(w1 & 0xFFFF) * 32 + l32];
    float4 c1 = rel4[(w1 >> 16) * 32 + l32];
    float4 a2 = ent4[(long)(w2 & 0xFFFF) * 32 + l32];
    float4 c2 = rel4[(w2 >> 16) * 32 + l32];
    float4 a3 = ent4[(long)(w3 & 0xFFFF) * 32 + l32];
    float4 c3 = rel4[(w3 >> 16) * 32 + l32];
    float4 q0, q1, q2, q3;
    q0.x = a0.x * c0.x; q0.y = a0.y * c0.y; q0.z = a0.z * c0.z; q0.w = a0.w * c0.w;
    q1.x = a1.x * c1.x; q1.y = a1.y * c1.y; q1.z = a1.z * c1.z; q1.w = a1.w * c1.w;
    q2.x = a2.x * c2.x; q2.y = a2.y * c2.y; q2.z = a2.z * c2.z; q2.w = a2.w * c2.w;
    q3.x = a3.x * c3.x; q3.y = a3.y * c3.y; q3.z = a3.z * c3.z; q3.w = a3.w * c3.w;
    float p0 = q0.x * b.x + q0.y * b.y + q0.z * b.z + q0.w * b.w;
    float p1 = q1.x * b.x + q1.y * b.y + q1.z * b.z + q1.w * b.w;
    float p2 = q2.x * b.x + q2.y * b.y + q2.z * b.z + q2.w * b.w;
    float p3 = q3.x * b.x + q3.y * b.y + q3.z * b.z + q3.w * b.w;
#pragma unroll
    for (int off = 16; off > 0; off >>= 1) {
      p0 += __shfl_xor(p0, off, 64);
      p1 += __shfl_xor(p1, off, 64);
      p2 += __shfl_xor(p2, off, 64);
      p3 += __shfl_xor(p3, off, 64);
    }
    float pm = fmaxf(fmaxf(fmaxf(p0, p1), fmaxf(p2, p3)), m);
    float f = __expf(m - pm);
    float e0 = __expf(p0 - pm);
    float e1 = __expf(p1 - pm);
    float e2 = __expf(p2 - pm);
    float e3 = __expf(p3 - pm);
    den = den * f + ((e0 + e1) + (e2 + e3));
    acc.x = acc.x * f + (q0.x * e0 + q1.x * e1) + (q2.x * e2 + q3.x * e3);
    acc.y = acc.y * f + (q0.y * e0 + q1.y * e1) + (q2.y * e2 + q3.y * e3);
    acc.z = acc.z * f + (q0.z * e0 + q1.z * e1) + (q2.z * e2 + q3.z * e3);
    acc.w = acc.w * f + (q0.w * e0 + q1.w * e1) + (q2.w * e2 + q3.w * e3);
    m = pm;
  }
  // 2 edges (1 per half)
  for (; s + 2 <= s1; s += 2) {
    int w = ei[s];
    float4 a = ent4[(long)(w & 0xFFFF) * 32 + l32];
    float4 c = rel4[(w >> 16) * 32 + l32];
    float4 q;
    q.x = a.x * c.x; q.y = a.y * c.y; q.z = a.z * c.z; q.w = a.w * c.w;
    float p = q.x * b.x + q.y * b.y + q.z * b.z + q.w * b.w;
#pragma unroll
    for (int off = 16; off > 0; off >>= 1) p += __shfl_xor(p, off, 64);
    float pm = fmaxf(p, m);
    float f = __expf(m - pm);
    float e = __expf(p - pm);
    den = den * f + e;
    acc.x = fmaf(acc.x, f, q.x * e);
    acc.y = fmaf(acc.y, f, q.y * e);
    acc.z = fmaf(acc.z, f, q.z * e);
    acc.w = fmaf(acc.w, f, q.w * e);
    m = pm;
  }
  // odd final edge: both halves compute it; half 1 contributes zero.
  if (s < s1) {
    int w = einfo[s];
    float4 a = ent4[(long)(w & 0xFFFF) * 32 + l32];
    float4 c = rel4[(w >> 16) * 32 + l32];
    float4 q;
    q.x = a.x * c.x; q.y = a.y * c.y; q.z = a.z * c.z; q.w = a.w * c.w;
    float p = q.x * b.x + q.y * b.y + q.z * b.z + q.w * b.w;
#pragma unroll
    for (int off = 16; off > 0; off >>= 1) p += __shfl_xor(p, off, 64);
    float pn = half ? -INFINITY : p;
    float pm = fmaxf(m, pn);
    float f = (m == -INFINITY) ? 0.f : __expf(m - pm);
    float e = (pn == -INFINITY) ? 0.f : __expf(pn - pm);
    den = den * f + e;
    acc.x = fmaf(acc.x, f, q.x * e);
    acc.y = fmaf(acc.y, f, q.y * e);
    acc.z = fmaf(acc.z, f, q.z * e);
    acc.w = fmaf(acc.w, f, q.w * e);
    m = pm;
  }
  // merge the two halves
  float mo = __shfl_xor(m, 32, 64);
  float deno = __shfl_xor(den, 32, 64);
  float4 acco;
  acco.x = __shfl_xor(acc.x, 32, 64);
  acco.y = __shfl_xor(acc.y, 32, 64);
  acco.z = __shfl_xor(acc.z, 32, 64);
  acco.w = __shfl_xor(acc.w, 32, 64);
  float mm = fmaxf(m, mo);
  float fs = (mm == -INFINITY) ? 0.f : __expf(m - mm);
  float fo = (mm == -INFINITY) ? 0.f : __expf(mo - mm);
  float dtot = den * fs + deno * fo;
  float inv = dtot > 0.f ? 1.f / dtot : 0.f;
  if (half == 0) {
    ushort4 o;
    o.x = f2h((acc.x * fs + acco.x * fo) * inv);
    o.y = f2h((acc.y * fs + acco.y * fo) * inv);
    o.z = f2h((acc.z * fs + acco.z * fo) * inv);
    o.w = f2h((acc.w * fs + acco.w * fo) * inv);
    ((ushort4*)(scaled_h + (long)n * HD))[l32] = o;
  }
}

// K_pre: W[k][col] f32 -> Wt[col][k] fp16 (LDS transpose, single block).
__global__ __launch_bounds__(256) void conv_w(const float* __restrict__ W,
                                              unsigned short* __restrict__ Wt) {
  __shared__ float sT[128 * 132];
  int tid = threadIdx.x;
  for (int i = tid; i < 4096; i += 256) {
    float4 v = ((const float4*)W)[i];
    int k = i >> 5, c = (i & 31) * 4;
    sT[k * 132 + c + 0] = v.x;
    sT[k * 132 + c + 1] = v.y;
    sT[k * 132 + c + 2] = v.z;
    sT[k * 132 + c + 3] = v.w;
  }
  __syncthreads();
  for (int o = tid; o < 128 * 128; o += 256) {
    int col = o >> 7, k = o & 127;
    Wt[o] = f2h(sT[k * 132 + col]);
  }
}

// K5: h = scaled_h @ W via MFMA fp16, stats fused.
// A: row=lane&15, k=(lane>>4)*8+i.  B: col=lane&15.  D: col=lane&15,
// row=(lane>>4)*4+r.
__global__ __launch_bounds__(256) void gemm_mfma(
    const unsigned short* __restrict__ scaled_h,
    const unsigned short* __restrict__ Wt, float* __restrict__ h,
    float* __restrict__ colsum, float* __restrict__ colsumsq) {
  __shared__ unsigned short sW[128 * 136];   // [col][k], pad->stride 136
  __shared__ unsigned short sA[4][16][144];  // [wave][row][k], stride 144
  int tid = threadIdx.x;
  int row0 = blockIdx.x * 64;

  for (int i = tid; i < 2048; i += 256) {
    int col = i >> 4, c8 = i & 15;
    *(int4*)&sW[col * 136 + c8 * 8] = ((const int4*)Wt)[i];
  }
  for (int i = tid; i < 1024; i += 256) {
    int r = i >> 4, c8 = i & 15;
    int gr = row0 + r;
    int4 v = make_int4(0, 0, 0, 0);
    if (gr < N_NODES) v = ((const int4*)(scaled_h + (long)gr * HD))[c8];
    *(int4*)&sA[r >> 4][r & 15][c8 * 8] = v;
  }
  __syncthreads();

  int w = tid >> 6, lane = tid & 63;
  int lrow = lane & 15, lk = lane >> 4;
  f32x4 acc[8];
#pragma unroll
  for (int n = 0; n < 8; ++n) acc[n] = (f32x4){0.f, 0.f, 0.f, 0.f};

#pragma unroll
  for (int kt = 0; kt < 4; ++kt) {
    half8 aF = *(const half8*)&sA[w][lrow][kt * 32 + lk * 8];
#pragma unroll
    for (int n = 0; n < 8; ++n) {
      half8 bF = *(const half8*)&sW[(n * 16 + lrow) * 136 + kt * 32 + lk * 8];
      acc[n] = __builtin_amdgcn_mfma_f32_16x16x32_f16(aF, bF, acc[n], 0, 0, 0);
    }
  }

  float s[8], q[8];
#pragma unroll
  for (int n = 0; n < 8; ++n) {
    int col = n * 16 + lrow;
    s[n] = 0.f;
    q[n] = 0.f;
#pragma unroll
    for (int r = 0; r < 4; ++r) {
      float v = acc[n][r];
      int grow = row0 + w * 16 + lk * 4 + r;
      if (grow < N_NODES) h[(long)grow * HD + col] = v;
      s[n] += v;
      q[n] += v * v;
    }
    s[n] += __shfl_xor(s[n], 16, 64);
    s[n] += __shfl_xor(s[n], 32, 64);
    q[n] += __shfl_xor(q[n], 16, 64);
    q[n] += __shfl_xor(q[n], 32, 64);
  }

  __syncthreads();
  float* sStat = (float*)&sA[0][0][0];
  sStat[tid] = 0.f;
  __syncthreads();
  if (lane < 16) {
#pragma unroll
    for (int n = 0; n < 8; ++n) {
      atomicAdd(&sStat[n * 16 + lrow], s[n]);
      atomicAdd(&sStat[128 + n * 16 + lrow], q[n]);
    }
  }
  __syncthreads();
  if (tid < 128) {
    unsafeAtomicAdd(colsum + tid, sStat[tid]);
    unsafeAtomicAdd(colsumsq + tid, sStat[128 + tid]);
  }
}

// K6: BN (batch stats) + tanh, in place on h (= d_out).
__global__ __launch_bounds__(256) void bn_tanh(
    float* __restrict__ h, const float* __restrict__ colsum,
    const float* __restrict__ colsumsq, const float* __restrict__ gamma,
    const float* __restrict__ beta) {
  const float invN = 1.f / (float)N_NODES;
  const int total4 = N_NODES * 32;
  for (int i = blockIdx.x * 256 + threadIdx.x; i < total4;
       i += gridDim.x * 256) {
    int c4 = i & 31;
    float4 hv = ((float4*)h)[i];
    float4 S = ((const float4*)colsum)[c4];
    float4 Q = ((const float4*)colsumsq)[c4];
    float4 G = ((const float4*)gamma)[c4];
    float4 B = ((const float4*)beta)[c4];
    float4 o;
    {
      float mu = S.x * invN, var = Q.x * invN - mu * mu;
      o.x = tanhf((hv.x - mu) * rsqrtf(var + BN_EPS) * G.x + B.x);
    }
    {
      float mu = S.y * invN, var = Q.y * invN - mu * mu;
      o.y = tanhf((hv.y - mu) * rsqrtf(var + BN_EPS) * G.y + B.y);
    }
    {
      float mu = S.z * invN, var = Q.z * invN - mu * mu;
      o.z = tanhf((hv.z - mu) * rsqrtf(var + BN_EPS) * G.z + B.z);
    }
    {
      float mu = S.w * invN, var = Q.w * invN - mu * mu;
      o.w = tanhf((hv.w - mu) * rsqrtf(var + BN_EPS) * G.w + B.w);
    }
    ((float4*)h)[i] = o;
  }
}

extern "C" void kernel_launch(void* const* d_in, const int* in_sizes, int n_in,
                              void* d_out, int out_size, void* d_ws, size_t ws_size,
                              hipStream_t stream) {
  const float* ent   = (const float*)d_in[0];
  const float* rel   = (const float*)d_in[1];
  const float* W     = (const float*)d_in[2];
  const float* gamma = (const float*)d_in[3];
  const float* beta  = (const float*)d_in[4];
  const int*   src   = (const int*)d_in[5];
  const int*   dst   = (const int*)d_in[6];
  const int*   rid   = (const int*)d_in[7];
  float* out = (float*)d_out;

  char* ws = (char*)d_ws;
  int* counts      = (int*)(ws + 0);           // 200,000 B
  int* cursor      = (int*)(ws + 200000);      // 200,000 B
  float* colsum    = (float*)(ws + 400000);    // 512 B
  float* colsumsq  = (float*)(ws + 400512);    // 512 B  (zeroed region ends 401,024)
  int* bsum        = (int*)(ws + 401024);      // 1,024 B
  int* bbase       = (int*)(ws + 402048);      // 1,024 B
  int* offsets     = (int*)(ws + 403072);      // 200,004 B -> 603,076
  unsigned short* Wt       = (unsigned short*)(ws + 603136);   // 32,768 B
  int* einfo               = (int*)(ws + 635904);              // 3,200,000 B
  unsigned short* scaled_h = (unsigned short*)(ws + 3835904);  // 12,800,000 B
  // total ws: 16,635,904 B;  h lives in d_out (bn_tanh in place)

  hipMemsetAsync(d_ws, 0, 401024, stream);

  hist<<<(N_EDGES / 4 + 255) / 256, 256, 0, stream>>>(dst, counts);
  scan_blocks<<<SCAN_NB, 256, 0, stream>>>(counts, bsum);
  scan_top<<<1, 64, 0, stream>>>(bsum, bbase, offsets);
  scan_write<<<SCAN_NB, 256, 0, stream>>>(counts, bbase, offsets);
  conv_w<<<1, 256, 0, stream>>>(W, Wt);
  fill_buckets<<<(N_EDGES / 4 + 255) / 256, 256, 0, stream>>>(src, dst, rid,
                                                              offsets, cursor, einfo);
  gather_fused<<<(N_NODES + 3) / 4, 256, 0, stream>>>(ent, rel, offsets, einfo,
                                                      scaled_h);
  gemm_mfma<<<(N_NODES + 63) / 64, 256, 0, stream>>>(scaled_h, Wt, out,
                                                     colsum, colsumsq);
  bn_tanh<<<2048, 256, 0, stream>>>(out, colsum, colsumsq, gamma, beta);
}

// Round 12
// 165.564 us; speedup vs baseline: 2.0476x; 1.2248x over previous
//
#include <hip/hip_runtime.h>
#include <hip/hip_fp16.h>
#include <math.h>

#define N_NODES 50000
#define N_EDGES 800000
#define HD 128
#define BN_EPS 1e-5f

#define SCAN_CHUNK 1024
#define SCAN_NB ((N_NODES + SCAN_CHUNK - 1) / SCAN_CHUNK)  // 49

typedef __attribute__((ext_vector_type(8))) _Float16 half8;
typedef __attribute__((ext_vector_type(4))) _Float16 h4;
typedef __attribute__((ext_vector_type(4))) float f32x4;

__device__ __forceinline__ unsigned short f2h(float f) {
  return __half_as_ushort(__float2half(f));
}

// K_pre: W[k][col] f32 -> Wt[col][k] fp16, 16 blocks of 32x32 tiles.
__global__ __launch_bounds__(256) void conv_w(const float* __restrict__ W,
                                              unsigned short* __restrict__ Wt) {
  __shared__ float sT[32][33];
  int k0 = (blockIdx.x >> 2) * 32, c0 = (blockIdx.x & 3) * 32;
  int tid = threadIdx.x;
  int kk = tid >> 3, cq = tid & 7;
  float4 v = ((const float4*)W)[(k0 + kk) * 32 + (c0 >> 2) + cq];
  sT[kk][cq * 4 + 0] = v.x;
  sT[kk][cq * 4 + 1] = v.y;
  sT[kk][cq * 4 + 2] = v.z;
  sT[kk][cq * 4 + 3] = v.w;
  __syncthreads();
  int cc = tid >> 3, kq = tid & 7;
  h4 o;
  o.x = (_Float16)sT[kq * 4 + 0][cc];
  o.y = (_Float16)sT[kq * 4 + 1][cc];
  o.z = (_Float16)sT[kq * 4 + 2][cc];
  o.w = (_Float16)sT[kq * 4 + 3][cc];
  ((h4*)(Wt + (c0 + cc) * HD + k0))[kq] = o;
}

// K1: dst-degree histogram + per-edge bucket rank (atomicAdd return value).
__global__ __launch_bounds__(256) void hist(const int* __restrict__ dst,
                                            int* __restrict__ counts,
                                            unsigned short* __restrict__ erank) {
  int i = blockIdx.x * 256 + threadIdx.x;
  if (i >= N_EDGES / 4) return;
  int4 d = ((const int4*)dst)[i];
  ushort4 r;
  r.x = (unsigned short)atomicAdd(counts + d.x, 1);
  r.y = (unsigned short)atomicAdd(counts + d.y, 1);
  r.z = (unsigned short)atomicAdd(counts + d.z, 1);
  r.w = (unsigned short)atomicAdd(counts + d.w, 1);
  ((ushort4*)erank)[i] = r;
}

// K2a/b/c: hierarchical exclusive scan of counts -> offsets, IN PLACE.
__global__ __launch_bounds__(256) void scan_blocks(
    const int* __restrict__ buf, int* __restrict__ bsum) {
  int t = threadIdx.x;
  int idx = blockIdx.x * SCAN_CHUNK + t * 4;
  int s = 0;
  if (idx + 3 < N_NODES) {
    int4 v = *(const int4*)(buf + idx);
    s = v.x + v.y + v.z + v.w;
  } else {
#pragma unroll
    for (int j = 0; j < 4; ++j)
      if (idx + j < N_NODES) s += buf[idx + j];
  }
  __shared__ int ls[256];
  ls[t] = s;
  __syncthreads();
  for (int off = 128; off > 0; off >>= 1) {
    if (t < off) ls[t] += ls[t + off];
    __syncthreads();
  }
  if (t == 0) bsum[blockIdx.x] = ls[0];
}

__global__ __launch_bounds__(64) void scan_top(const int* __restrict__ bsum,
                                               int* __restrict__ bbase,
                                               int* buf) {
  int t = threadIdx.x;
  int v = (t < SCAN_NB) ? bsum[t] : 0;
  int incl = v;
#pragma unroll
  for (int off = 1; off < 64; off <<= 1) {
    int u = __shfl_up(incl, off, 64);
    if (t >= off) incl += u;
  }
  if (t < SCAN_NB) bbase[t] = incl - v;
  if (t == 63) buf[N_NODES] = incl;
}

__global__ __launch_bounds__(256) void scan_write(int* buf,
                                                  const int* __restrict__ bbase) {
  int t = threadIdx.x;
  int idx = blockIdx.x * SCAN_CHUNK + t * 4;
  int c[4] = {0, 0, 0, 0};
  if (idx + 3 < N_NODES) {
    int4 v = *(const int4*)(buf + idx);
    c[0] = v.x; c[1] = v.y; c[2] = v.z; c[3] = v.w;
  } else {
#pragma unroll
    for (int j = 0; j < 4; ++j)
      if (idx + j < N_NODES) c[j] = buf[idx + j];
  }
  int s = c[0] + c[1] + c[2] + c[3];
  __shared__ int ls[256];
  ls[t] = s;
  __syncthreads();
  for (int off = 1; off < 256; off <<= 1) {
    int u = (t >= off) ? ls[t - off] : 0;
    __syncthreads();
    ls[t] += u;
    __syncthreads();
  }
  int run = bbase[blockIdx.x] + ls[t] - s;
#pragma unroll
  for (int j = 0; j < 4; ++j) {
    if (idx + j < N_NODES) {
      buf[idx + j] = run;
      run += c[j];
    }
  }
}

// K3: bucket edges by dst using precomputed ranks (atomic-free).
// Record packed to 4B: src | (rid<<16).
__global__ __launch_bounds__(256) void fill_buckets(
    const int* __restrict__ src, const int* __restrict__ dst,
    const int* __restrict__ rid, const unsigned short* __restrict__ erank,
    const int* __restrict__ offsets, int* __restrict__ einfo) {
  int i = blockIdx.x * 256 + threadIdx.x;
  if (i >= N_EDGES / 4) return;
  int4 s4 = ((const int4*)src)[i];
  int4 d4 = ((const int4*)dst)[i];
  int4 r4 = ((const int4*)rid)[i];
  ushort4 k4 = ((const ushort4*)erank)[i];
#pragma unroll
  for (int q = 0; q < 4; ++q) {
    int s = (q == 0) ? s4.x : (q == 1) ? s4.y : (q == 2) ? s4.z : s4.w;
    int d = (q == 0) ? d4.x : (q == 1) ? d4.y : (q == 2) ? d4.z : d4.w;
    int r = (q == 0) ? r4.x : (q == 1) ? r4.y : (q == 2) ? r4.z : r4.w;
    int k = (q == 0) ? k4.x : (q == 1) ? k4.y : (q == 2) ? k4.z : k4.w;
    einfo[offsets[d] + k] = s | (r << 16);
  }
}

// K4: fused score + online-softmax + aggregation (fp32 gathers, proven
// 0.0039 absmax).  One wave per dst node, two 32-lane halves with
// independent state; 8 edges per unrolled iteration (4 per half).
// Writes scaled rows as fp16 for the MFMA GEMM.
__global__ __launch_bounds__(256) void gather_fused(
    const float* __restrict__ ent, const float* __restrict__ rel,
    const int* __restrict__ offsets, const int* __restrict__ einfo,
    unsigned short* __restrict__ scaled_h) {
  int n = blockIdx.x * 4 + (threadIdx.x >> 6);
  if (n >= N_NODES) return;
  int lane = threadIdx.x & 63;
  int half = lane >> 5;
  int l32 = lane & 31;
  int s0 = __builtin_amdgcn_readfirstlane(offsets[n]);
  int s1 = __builtin_amdgcn_readfirstlane(offsets[n + 1]);
  const float4* ent4 = (const float4*)ent;
  const float4* rel4 = (const float4*)rel;
  float4 b = ent4[(long)n * 32 + l32];
  const int* ei = einfo + half;

  float m = -INFINITY, den = 0.f;
  float4 acc = make_float4(0.f, 0.f, 0.f, 0.f);
  int s = s0;
  // 8 edges per iteration (4 per half): 8 row-loads in flight per half.
  for (; s + 8 <= s1; s += 8) {
    int w0 = ei[s + 0];
    int w1 = ei[s + 2];
    int w2 = ei[s + 4];
    int w3 = ei[s + 6];
    float4 a0 = ent4[(long)(w0 & 0xFFFF) * 32 + l32];
    float4 c0 = rel4[(w0 >> 16) * 32 + l32];
    float4 a1 = ent4[(long)(w1 & 0xFFFF) * 32 + l32];
    float4 c1 = rel4[(w1 >> 16) * 32 + l32];
    float4 a2 = ent4[(long)(w2 & 0xFFFF) * 32 + l32];
    float4 c2 = rel4[(w2 >> 16) * 32 + l32];
    float4 a3 = ent4[(long)(w3 & 0xFFFF) * 32 + l32];
    float4 c3 = rel4[(w3 >> 16) * 32 + l32];
    float4 q0, q1, q2, q3;
    q0.x = a0.x * c0.x; q0.y = a0.y * c0.y; q0.z = a0.z * c0.z; q0.w = a0.w * c0.w;
    q1.x = a1.x * c1.x; q1.y = a1.y * c1.y; q1.z = a1.z * c1.z; q1.w = a1.w * c1.w;
    q2.x = a2.x * c2.x; q2.y = a2.y * c2.y; q2.z = a2.z * c2.z; q2.w = a2.w * c2.w;
    q3.x = a3.x * c3.x; q3.y = a3.y * c3.y; q3.z = a3.z * c3.z; q3.w = a3.w * c3.w;
    float p0 = q0.x * b.x + q0.y * b.y + q0.z * b.z + q0.w * b.w;
    float p1 = q1.x * b.x + q1.y * b.y + q1.z * b.z + q1.w * b.w;
    float p2 = q2.x * b.x + q2.y * b.y + q2.z * b.z + q2.w * b.w;
    float p3 = q3.x * b.x + q3.y * b.y + q3.z * b.z + q3.w * b.w;
#pragma unroll
    for (int off = 16; off > 0; off >>= 1) {
      p0 += __shfl_xor(p0, off, 64);
      p1 += __shfl_xor(p1, off, 64);
      p2 += __shfl_xor(p2, off, 64);
      p3 += __shfl_xor(p3, off, 64);
    }
    float pm = fmaxf(fmaxf(fmaxf(p0, p1), fmaxf(p2, p3)), m);
    float f = __expf(m - pm);
    float e0 = __expf(p0 - pm);
    float e1 = __expf(p1 - pm);
    float e2 = __expf(p2 - pm);
    float e3 = __expf(p3 - pm);
    den = den * f + ((e0 + e1) + (e2 + e3));
    acc.x = acc.x * f + (q0.x * e0 + q1.x * e1) + (q2.x * e2 + q3.x * e3);
    acc.y = acc.y * f + (q0.y * e0 + q1.y * e1) + (q2.y * e2 + q3.y * e3);
    acc.z = acc.z * f + (q0.z * e0 + q1.z * e1) + (q2.z * e2 + q3.z * e3);
    acc.w = acc.w * f + (q0.w * e0 + q1.w * e1) + (q2.w * e2 + q3.w * e3);
    m = pm;
  }
  // 2 edges (1 per half)
  for (; s + 2 <= s1; s += 2) {
    int w = ei[s];
    float4 a = ent4[(long)(w & 0xFFFF) * 32 + l32];
    float4 c = rel4[(w >> 16) * 32 + l32];
    float4 q;
    q.x = a.x * c.x; q.y = a.y * c.y; q.z = a.z * c.z; q.w = a.w * c.w;
    float p = q.x * b.x + q.y * b.y + q.z * b.z + q.w * b.w;
#pragma unroll
    for (int off = 16; off > 0; off >>= 1) p += __shfl_xor(p, off, 64);
    float pm = fmaxf(p, m);
    float f = __expf(m - pm);
    float e = __expf(p - pm);
    den = den * f + e;
    acc.x = fmaf(acc.x, f, q.x * e);
    acc.y = fmaf(acc.y, f, q.y * e);
    acc.z = fmaf(acc.z, f, q.z * e);
    acc.w = fmaf(acc.w, f, q.w * e);
    m = pm;
  }
  // odd final edge: both halves compute it; half 1 contributes zero.
  if (s < s1) {
    int w = einfo[s];
    float4 a = ent4[(long)(w & 0xFFFF) * 32 + l32];
    float4 c = rel4[(w >> 16) * 32 + l32];
    float4 q;
    q.x = a.x * c.x; q.y = a.y * c.y; q.z = a.z * c.z; q.w = a.w * c.w;
    float p = q.x * b.x + q.y * b.y + q.z * b.z + q.w * b.w;
#pragma unroll
    for (int off = 16; off > 0; off >>= 1) p += __shfl_xor(p, off, 64);
    float pn = half ? -INFINITY : p;
    float pm = fmaxf(m, pn);
    float f = (m == -INFINITY) ? 0.f : __expf(m - pm);
    float e = (pn == -INFINITY) ? 0.f : __expf(pn - pm);
    den = den * f + e;
    acc.x = fmaf(acc.x, f, q.x * e);
    acc.y = fmaf(acc.y, f, q.y * e);
    acc.z = fmaf(acc.z, f, q.z * e);
    acc.w = fmaf(acc.w, f, q.w * e);
    m = pm;
  }
  // merge the two halves
  float mo = __shfl_xor(m, 32, 64);
  float deno = __shfl_xor(den, 32, 64);
  float4 acco;
  acco.x = __shfl_xor(acc.x, 32, 64);
  acco.y = __shfl_xor(acc.y, 32, 64);
  acco.z = __shfl_xor(acc.z, 32, 64);
  acco.w = __shfl_xor(acc.w, 32, 64);
  float mm = fmaxf(m, mo);
  float fs = (mm == -INFINITY) ? 0.f : __expf(m - mm);
  float fo = (mm == -INFINITY) ? 0.f : __expf(mo - mm);
  float dtot = den * fs + deno * fo;
  float inv = dtot > 0.f ? 1.f / dtot : 0.f;
  if (half == 0) {
    ushort4 o;
    o.x = f2h((acc.x * fs + acco.x * fo) * inv);
    o.y = f2h((acc.y * fs + acco.y * fo) * inv);
    o.z = f2h((acc.z * fs + acco.z * fo) * inv);
    o.w = f2h((acc.w * fs + acco.w * fo) * inv);
    ((ushort4*)(scaled_h + (long)n * HD))[l32] = o;
  }
}

// K5: h = scaled_h @ W via MFMA fp16, stats fused.  A-fragments loaded
// directly from global (rows block-exclusive, read once); only W in LDS.
__global__ __launch_bounds__(256) void gemm_mfma(
    const unsigned short* __restrict__ scaled_h,
    const unsigned short* __restrict__ Wt, float* __restrict__ h,
    float* __restrict__ colsum, float* __restrict__ colsumsq) {
  __shared__ unsigned short sW[128 * 136];  // [col][k], pad->stride 136
  __shared__ float sStat[256];
  int tid = threadIdx.x;
  int row0 = blockIdx.x * 64;

  for (int i = tid; i < 2048; i += 256) {
    int col = i >> 4, c8 = i & 15;
    *(int4*)&sW[col * 136 + c8 * 8] = ((const int4*)Wt)[i];
  }
  __syncthreads();

  int w = tid >> 6, lane = tid & 63;
  int lrow = lane & 15, lk = lane >> 4;
  int arow = row0 + w * 16 + lrow;
  bool avalid = arow < N_NODES;
  const half8* ap = (const half8*)(scaled_h + (long)(avalid ? arow : 0) * HD);

  f32x4 acc[8];
#pragma unroll
  for (int n = 0; n < 8; ++n) acc[n] = (f32x4){0.f, 0.f, 0.f, 0.f};

#pragma unroll
  for (int kt = 0; kt < 4; ++kt) {
    half8 aF = avalid ? ap[kt * 4 + lk]
                      : (half8){(_Float16)0, (_Float16)0, (_Float16)0, (_Float16)0,
                                (_Float16)0, (_Float16)0, (_Float16)0, (_Float16)0};
#pragma unroll
    for (int n = 0; n < 8; ++n) {
      half8 bF = *(const half8*)&sW[(n * 16 + lrow) * 136 + kt * 32 + lk * 8];
      acc[n] = __builtin_amdgcn_mfma_f32_16x16x32_f16(aF, bF, acc[n], 0, 0, 0);
    }
  }

  float s[8], q[8];
#pragma unroll
  for (int n = 0; n < 8; ++n) {
    int col = n * 16 + lrow;
    s[n] = 0.f;
    q[n] = 0.f;
#pragma unroll
    for (int r = 0; r < 4; ++r) {
      float v = acc[n][r];
      int grow = row0 + w * 16 + lk * 4 + r;
      if (grow < N_NODES) h[(long)grow * HD + col] = v;
      s[n] += v;
      q[n] += v * v;
    }
    s[n] += __shfl_xor(s[n], 16, 64);
    s[n] += __shfl_xor(s[n], 32, 64);
    q[n] += __shfl_xor(q[n], 16, 64);
    q[n] += __shfl_xor(q[n], 32, 64);
  }

  sStat[tid] = 0.f;
  __syncthreads();
  if (lane < 16) {
#pragma unroll
    for (int n = 0; n < 8; ++n) {
      atomicAdd(&sStat[n * 16 + lrow], s[n]);
      atomicAdd(&sStat[128 + n * 16 + lrow], q[n]);
    }
  }
  __syncthreads();
  if (tid < 128) {
    unsafeAtomicAdd(colsum + tid, sStat[tid]);
    unsafeAtomicAdd(colsumsq + tid, sStat[128 + tid]);
  }
}

// K6: BN (batch stats) + tanh, in place on h (= d_out).
__global__ __launch_bounds__(256) void bn_tanh(
    float* __restrict__ h, const float* __restrict__ colsum,
    const float* __restrict__ colsumsq, const float* __restrict__ gamma,
    const float* __restrict__ beta) {
  const float invN = 1.f / (float)N_NODES;
  const int total4 = N_NODES * 32;
  for (int i = blockIdx.x * 256 + threadIdx.x; i < total4;
       i += gridDim.x * 256) {
    int c4 = i & 31;
    float4 hv = ((float4*)h)[i];
    float4 S = ((const float4*)colsum)[c4];
    float4 Q = ((const float4*)colsumsq)[c4];
    float4 G = ((const float4*)gamma)[c4];
    float4 B = ((const float4*)beta)[c4];
    float4 o;
    {
      float mu = S.x * invN, var = Q.x * invN - mu * mu;
      o.x = tanhf((hv.x - mu) * rsqrtf(var + BN_EPS) * G.x + B.x);
    }
    {
      float mu = S.y * invN, var = Q.y * invN - mu * mu;
      o.y = tanhf((hv.y - mu) * rsqrtf(var + BN_EPS) * G.y + B.y);
    }
    {
      float mu = S.z * invN, var = Q.z * invN - mu * mu;
      o.z = tanhf((hv.z - mu) * rsqrtf(var + BN_EPS) * G.z + B.z);
    }
    {
      float mu = S.w * invN, var = Q.w * invN - mu * mu;
      o.w = tanhf((hv.w - mu) * rsqrtf(var + BN_EPS) * G.w + B.w);
    }
    ((float4*)h)[i] = o;
  }
}

extern "C" void kernel_launch(void* const* d_in, const int* in_sizes, int n_in,
                              void* d_out, int out_size, void* d_ws, size_t ws_size,
                              hipStream_t stream) {
  const float* ent   = (const float*)d_in[0];
  const float* rel   = (const float*)d_in[1];
  const float* W     = (const float*)d_in[2];
  const float* gamma = (const float*)d_in[3];
  const float* beta  = (const float*)d_in[4];
  const int*   src   = (const int*)d_in[5];
  const int*   dst   = (const int*)d_in[6];
  const int*   rid   = (const int*)d_in[7];
  float* out = (float*)d_out;

  char* ws = (char*)d_ws;
  // counts scanned IN PLACE into offsets; buf[N_NODES] = total.
  int* offsets     = (int*)(ws + 0);                          // 200,064 B
  float* colsum    = (float*)(ws + 200064);                   // 512 B
  float* colsumsq  = (float*)(ws + 200576);                   // 512 B
  int* bsum        = (int*)(ws + 201088);                     // 1,024 B
  int* bbase       = (int*)(ws + 202112);                     // 1,024 B
  unsigned short* Wt = (unsigned short*)(ws + 203136);        // 32,768 B
  int* einfo         = (int*)(ws + 235904);                   // 3,200,000 B
  // erank (1.6 MB) and scaled_h (12.8 MB) share a region: erank is dead
  // before gather writes scaled_h (strict stream ordering).
  unsigned short* erank    = (unsigned short*)(ws + 3435904); // 1,600,000 B
  unsigned short* scaled_h = (unsigned short*)(ws + 3435904); // 12,800,000 B
  // total ws: 16,235,904 B;  h lives in d_out (bn_tanh in place)

  // zero: counts (offsets buf) + colsum + colsumsq
  hipMemsetAsync(d_ws, 0, 201088, stream);

  conv_w<<<16, 256, 0, stream>>>(W, Wt);
  hist<<<(N_EDGES / 4 + 255) / 256, 256, 0, stream>>>(dst, offsets, erank);
  scan_blocks<<<SCAN_NB, 256, 0, stream>>>(offsets, bsum);
  scan_top<<<1, 64, 0, stream>>>(bsum, bbase, offsets);
  scan_write<<<SCAN_NB, 256, 0, stream>>>(offsets, bbase);
  fill_buckets<<<(N_EDGES / 4 + 255) / 256, 256, 0, stream>>>(
      src, dst, rid, erank, offsets, einfo);
  gather_fused<<<(N_NODES + 3) / 4, 256, 0, stream>>>(ent, rel, offsets,
                                                      einfo, scaled_h);
  gemm_mfma<<<(N_NODES + 63) / 64, 256, 0, stream>>>(scaled_h, Wt, out,
                                                     colsum, colsumsq);
  bn_tanh<<<2048, 256, 0, stream>>>(out, colsum, colsumsq, gamma, beta);
}